// Round 7
// baseline (623.671 us; speedup 1.0000x reference)
//
#include <hip/hip_runtime.h>
#include <math.h>
#include <stdint.h>

// Problem constants
#define Bb 4
#define Lc 2048
#define Dm 512
#define Ei 1024     // E = 2*D_MODEL
#define Ns 16       // d_state
#define Rr 32       // dt_rank
#define EPSf 1e-5f
#define NCH 16      // scan chunks
#define TCH 128     // timesteps per chunk
#define LDS_S 40    // padded LDS row stride (ushorts) for MFMA tiles

typedef __attribute__((ext_vector_type(8))) short bf16x8;
typedef __attribute__((ext_vector_type(4))) float f32x4;

__device__ __forceinline__ float siluf(float x) {
    return x / (1.f + __expf(-x));
}
__device__ __forceinline__ float softplusf(float x) {
    return x > 20.f ? x : log1pf(__expf(x));
}
__device__ __forceinline__ unsigned short f2bf(float x) {
    union { float f; unsigned u; } v; v.f = x;
    unsigned r = (v.u + 0x7FFFu + ((v.u >> 16) & 1u)) >> 16;
    return (unsigned short)r;
}
__device__ __forceinline__ float bf2f(unsigned short x) {
    union { unsigned u; float f; } v; v.u = ((unsigned)x) << 16;
    return v.f;
}

// ---------------------------------------------------------------------------
// K1: LayerNorm -> bf16 h. One wave per row (D=512), 4 rows/block.
// ---------------------------------------------------------------------------
__global__ __launch_bounds__(256) void k_ln(const float* __restrict__ inp,
                                            const float* __restrict__ nw,
                                            const float* __restrict__ nb,
                                            unsigned short* __restrict__ hbf) {
    int row  = blockIdx.x * 4 + (threadIdx.x >> 6);
    int lane = threadIdx.x & 63;
    const float4* p = (const float4*)(inp + (size_t)row * Dm);
    float4 v0 = p[lane];
    float4 v1 = p[lane + 64];
    float s = v0.x + v0.y + v0.z + v0.w + v1.x + v1.y + v1.z + v1.w;
    float q = v0.x * v0.x + v0.y * v0.y + v0.z * v0.z + v0.w * v0.w +
              v1.x * v1.x + v1.y * v1.y + v1.z * v1.z + v1.w * v1.w;
#pragma unroll
    for (int off = 32; off >= 1; off >>= 1) {
        s += __shfl_xor(s, off);
        q += __shfl_xor(q, off);
    }
    float mu = s * (1.f / Dm);
    float rs = rsqrtf(q * (1.f / Dm) - mu * mu + EPSf);
    int d0 = lane * 4, d1 = 256 + lane * 4;
    float4 w0 = *(const float4*)&nw[d0], w1 = *(const float4*)&nw[d1];
    float4 b0 = *(const float4*)&nb[d0], b1 = *(const float4*)&nb[d1];
    ushort4 o0, o1;
    o0.x = f2bf((v0.x - mu) * rs * w0.x + b0.x);
    o0.y = f2bf((v0.y - mu) * rs * w0.y + b0.y);
    o0.z = f2bf((v0.z - mu) * rs * w0.z + b0.z);
    o0.w = f2bf((v0.w - mu) * rs * w0.w + b0.w);
    o1.x = f2bf((v1.x - mu) * rs * w1.x + b1.x);
    o1.y = f2bf((v1.y - mu) * rs * w1.y + b1.y);
    o1.z = f2bf((v1.z - mu) * rs * w1.z + b1.z);
    o1.w = f2bf((v1.w - mu) * rs * w1.w + b1.w);
    *(ushort4*)&hbf[(size_t)row * Dm + d0] = o0;
    *(ushort4*)&hbf[(size_t)row * Dm + d1] = o1;
}

// ---------------------------------------------------------------------------
// K1b: merged fp32 -> bf16 cast of all four weight tensors. Quad-indexed.
// ---------------------------------------------------------------------------
__global__ __launch_bounds__(256) void k_castall(
    const float* __restrict__ Win,  unsigned short* __restrict__ wbi,
    const float* __restrict__ Wout, unsigned short* __restrict__ wbo,
    const float* __restrict__ xpf,  unsigned short* __restrict__ xpbf,
    const float* __restrict__ xpr,  unsigned short* __restrict__ xpbr) {
    size_t q = (size_t)blockIdx.x * 256 + threadIdx.x;  // quad index
    const float* src; unsigned short* dst; size_t off;
    if (q < 262144)      { src = Win;  dst = wbi;  off = q; }
    else if (q < 393216) { src = Wout; dst = wbo;  off = q - 262144; }
    else if (q < 409600) { src = xpf;  dst = xpbf; off = q - 393216; }
    else                 { src = xpr;  dst = xpbr; off = q - 409600; }
    float4 v = ((const float4*)src)[off];
    ushort4 o;
    o.x = f2bf(v.x); o.y = f2bf(v.y); o.z = f2bf(v.z); o.w = f2bf(v.w);
    ((ushort4*)dst)[off] = o;
}

// ---------------------------------------------------------------------------
// K2: in_proj bf16 MFMA GEMM.  xz[b][m][n] = sum_k W[m][k] * h[b*L+n][k]
// Output now bf16.
// ---------------------------------------------------------------------------
__global__ __launch_bounds__(256) void k_mfma_inproj(
    const unsigned short* __restrict__ Wbf,  // (2048,512) bf16
    const unsigned short* __restrict__ hbf,  // (8192,512) bf16
    unsigned short* __restrict__ xz)         // (4,2048,2048) bf16
{
    const int b  = blockIdx.z;
    const int m0 = blockIdx.x * 128;
    const int n0 = blockIdx.y * 128;
    __shared__ __align__(16) unsigned short lA[128 * LDS_S];
    __shared__ __align__(16) unsigned short lB[128 * LDS_S];
    const int tid  = threadIdx.x;
    const int lane = tid & 63;
    const int w    = tid >> 6;
    const int wr   = w >> 1, wc = w & 1;

    f32x4 acc[4][4] = {};

    const unsigned short* hb = hbf + ((size_t)b * Lc + n0) * Dm;
    const unsigned short* Wb = Wbf + (size_t)m0 * Dm;

    for (int k0 = 0; k0 < Dm; k0 += 32) {
#pragma unroll
        for (int i = 0; i < 2; i++) {
            int c = tid + i * 256;            // 512 16B-chunks per tile
            int row = c >> 2, col = (c & 3) * 8;
            *(uint4*)&lA[row * LDS_S + col] = *(const uint4*)&Wb[(size_t)row * Dm + k0 + col];
            *(uint4*)&lB[row * LDS_S + col] = *(const uint4*)&hb[(size_t)row * Dm + k0 + col];
        }
        __syncthreads();
        bf16x8 aF[4], bF[4];
#pragma unroll
        for (int f = 0; f < 4; f++) {
            aF[f] = *(bf16x8*)&lA[(wr * 64 + f * 16 + (lane & 15)) * LDS_S + (lane >> 4) * 8];
            bF[f] = *(bf16x8*)&lB[(wc * 64 + f * 16 + (lane & 15)) * LDS_S + (lane >> 4) * 8];
        }
#pragma unroll
        for (int i = 0; i < 4; i++)
#pragma unroll
            for (int j = 0; j < 4; j++)
                acc[i][j] = __builtin_amdgcn_mfma_f32_16x16x32_bf16(aF[i], bF[j], acc[i][j], 0, 0, 0);
        __syncthreads();
    }
    unsigned short* Cb = xz + (size_t)b * 2048 * Lc;
#pragma unroll
    for (int i = 0; i < 4; i++) {
        int mbase = m0 + wr * 64 + i * 16 + (lane >> 4) * 4;
#pragma unroll
        for (int j = 0; j < 4; j++) {
            int nn = n0 + wc * 64 + j * 16 + (lane & 15);
#pragma unroll
            for (int r = 0; r < 4; r++)
                Cb[(size_t)(mbase + r) * Lc + nn] = f2bf(acc[i][j][r]);
        }
    }
}

// ---------------------------------------------------------------------------
// K3: tiled causal depthwise conv (K=4) + SiLU on bf16 xz.
// Emits ONLY xcT [b][L][e] bf16 via LDS transpose tile.
// Block: 16 e x 64 l.  Grid (L/64, E/16, B).
// ---------------------------------------------------------------------------
__global__ __launch_bounds__(256) void k_conv(const unsigned short* __restrict__ xz,
                                              const float* __restrict__ cw,
                                              const float* __restrict__ cb,
                                              unsigned short* __restrict__ xcT,
                                              int rev) {
    const int b  = blockIdx.z;
    const int e0 = blockIdx.y * 16;
    const int t0 = blockIdx.x * 64;
    const int tid = threadIdx.x;
    const int g = tid >> 4;
    const int n = tid & 15;
    const int e = e0 + g;
    const int j0 = t0 + n * 4;

    __shared__ unsigned short sY[64][20];   // stride 40 B: ushort4-aligned rows

    const unsigned short* x = xz + ((size_t)b * 2048 + e) * Lc;
    float w0 = cw[e * 4], w1 = cw[e * 4 + 1], w2 = cw[e * 4 + 2], w3 = cw[e * 4 + 3];
    float bias = cb[e];

    float v[8];  // xin[j0-4 .. j0+3] (xin = x or reversed x)
    if (!rev) {
        ushort4 cur = *(const ushort4*)&x[j0];
        v[4] = bf2f(cur.x); v[5] = bf2f(cur.y); v[6] = bf2f(cur.z); v[7] = bf2f(cur.w);
        if (j0 >= 4) {
            ushort4 prv = *(const ushort4*)&x[j0 - 4];
            v[0] = bf2f(prv.x); v[1] = bf2f(prv.y); v[2] = bf2f(prv.z); v[3] = bf2f(prv.w);
        } else { v[0] = v[1] = v[2] = v[3] = 0.f; }
    } else {
        ushort4 c4 = *(const ushort4*)&x[Lc - 4 - j0];   // x[Lc-4-j0 .. Lc-1-j0]
        v[4] = bf2f(c4.w); v[5] = bf2f(c4.z); v[6] = bf2f(c4.y); v[7] = bf2f(c4.x);
        if (j0 >= 4) {
            ushort4 p4 = *(const ushort4*)&x[Lc - j0];   // xin[j0-1..j0-4] fwd order
            v[0] = bf2f(p4.w); v[1] = bf2f(p4.z); v[2] = bf2f(p4.y); v[3] = bf2f(p4.x);
        } else { v[0] = v[1] = v[2] = v[3] = 0.f; }
    }

#pragma unroll
    for (int jj = 0; jj < 4; jj++) {
        float a = bias + w0 * v[jj + 1] + w1 * v[jj + 2] + w2 * v[jj + 3] + w3 * v[jj + 4];
        sY[n * 4 + jj][g] = f2bf(siluf(a));
    }
    __syncthreads();

    // transpose-tile write: [l][e] rows of 16 e (32 B per row)
    int row = tid >> 2;
    int c4  = (tid & 3) * 4;
    ushort4 tv = *(ushort4*)&sY[row][c4];
    *(ushort4*)&xcT[((size_t)b * Lc + t0 + row) * Ei + e0 + c4] = tv;
}

// ---------------------------------------------------------------------------
// K4: x_proj bf16 MFMA GEMM: xdbl[b][m][n] = sum_e xpw[m][e] * xcT[b][n][e]
// ---------------------------------------------------------------------------
__global__ __launch_bounds__(256) void k_mfma_xdbl(
    const unsigned short* __restrict__ xpb,  // (64,1024) bf16
    const unsigned short* __restrict__ xcT,  // (4,2048,1024) bf16
    float* __restrict__ xdbl)                // (4,64,2048)
{
    const int n0 = blockIdx.x * 128;
    const int b  = blockIdx.y;
    __shared__ __align__(16) unsigned short lA[64 * LDS_S];
    __shared__ __align__(16) unsigned short lB[128 * LDS_S];
    const int tid  = threadIdx.x;
    const int lane = tid & 63;
    const int w    = tid >> 6;

    f32x4 acc[4][2] = {};

    const unsigned short* yb = xcT + ((size_t)b * Lc + n0) * Ei;

    for (int k0 = 0; k0 < Ei; k0 += 32) {
        {
            int c = tid;                     // A: 64 rows x 4 chunks
            int row = c >> 2, col = (c & 3) * 8;
            *(uint4*)&lA[row * LDS_S + col] = *(const uint4*)&xpb[(size_t)row * Ei + k0 + col];
        }
#pragma unroll
        for (int i = 0; i < 2; i++) {
            int c = tid + i * 256;           // B: 128 rows x 4 chunks
            int row = c >> 2, col = (c & 3) * 8;
            *(uint4*)&lB[row * LDS_S + col] = *(const uint4*)&yb[(size_t)row * Ei + k0 + col];
        }
        __syncthreads();
        bf16x8 aF[4], bF[2];
#pragma unroll
        for (int f = 0; f < 4; f++)
            aF[f] = *(bf16x8*)&lA[(f * 16 + (lane & 15)) * LDS_S + (lane >> 4) * 8];
#pragma unroll
        for (int f = 0; f < 2; f++)
            bF[f] = *(bf16x8*)&lB[(w * 32 + f * 16 + (lane & 15)) * LDS_S + (lane >> 4) * 8];
#pragma unroll
        for (int i = 0; i < 4; i++)
#pragma unroll
            for (int j = 0; j < 2; j++)
                acc[i][j] = __builtin_amdgcn_mfma_f32_16x16x32_bf16(aF[i], bF[j], acc[i][j], 0, 0, 0);
        __syncthreads();
    }
    float* xd = xdbl + (size_t)b * 64 * Lc;
#pragma unroll
    for (int i = 0; i < 4; i++) {
        int mbase = i * 16 + (lane >> 4) * 4;
#pragma unroll
        for (int j = 0; j < 2; j++) {
            int nn = n0 + w * 32 + j * 16 + (lane & 15);
#pragma unroll
            for (int r = 0; r < 4; r++)
                xd[(size_t)(mbase + r) * Lc + nn] = acc[i][j][r];
        }
    }
}

// ---------------------------------------------------------------------------
// K4b: dt = softplus(dtw @ dt_low + bias).  Output bf16 [b][t][e] via LDS
// transpose tile.  Block: 16 e x 64 t.  Grid (32, 64, 4).
// ---------------------------------------------------------------------------
__global__ __launch_bounds__(256) void k_dt(
    const float* __restrict__ xdbl,  // (4,64,2048); rows 0..31 = dt_low
    const float* __restrict__ dtw,   // (1024,32)
    const float* __restrict__ dtb,   // (1024)
    unsigned short* __restrict__ dt16) // (4,2048,1024) bf16 [t][e]
{
    const int b  = blockIdx.z;
    const int e0 = blockIdx.y * 16;
    const int t0 = blockIdx.x * 64;
    const int tid = threadIdx.x;
    const int g = tid >> 4;          // local e
    const int n = tid & 15;          // t-quad selector
    const int e = e0 + g;

    __shared__ float sW[16][33];
    __shared__ float sDtl[32][68];
    __shared__ unsigned short sT[64][20];

    for (int i = tid; i < 512; i += 256)
        sW[i >> 5][i & 31] = dtw[(size_t)(e0 + (i >> 5)) * 32 + (i & 31)];

    const float* xdb = xdbl + (size_t)b * 64 * Lc;
#pragma unroll
    for (int f = 0; f < 2; f++) {
        int fi = tid * 2 + f;            // 512 float4 slots (32 rows x 16 quads)
        int row = fi >> 4, c4 = (fi & 15) * 4;
        *(float4*)&sDtl[row][c4] = *(const float4*)&xdb[(size_t)row * Lc + t0 + c4];
    }
    __syncthreads();

    const float bias = dtb[e];
#pragma unroll
    for (int jj = 0; jj < 4; jj++) {
        int tt = n * 4 + jj;
        float a = bias;
#pragma unroll
        for (int r = 0; r < 32; r++) a += sDtl[r][tt] * sW[g][r];
        sT[tt][g] = f2bf(softplusf(a));
    }
    __syncthreads();

    int row = tid >> 2;
    int c4  = (tid & 3) * 4;
    ushort4 tv = *(ushort4*)&sT[row][c4];
    *(ushort4*)&dt16[((size_t)b * Lc + t0 + row) * Ei + e0 + c4] = tv;
}

// ---------------------------------------------------------------------------
// K5a: scan pass 1 — per-chunk affine transform (P = prod dA, S = local h).
// u/dt staged from [t][e] tiles; B rows prefetched to registers (L2-hot).
// ---------------------------------------------------------------------------
__global__ __launch_bounds__(256) void k_scan_p1(
    const unsigned short* __restrict__ xcT,   // u bf16 [b][t][e]
    const float* __restrict__ xdbl,
    const unsigned short* __restrict__ dt16,  // bf16 [b][t][e]
    const float* __restrict__ Alog,
    float* __restrict__ Pbuf,          // [NCH][4][1024][16]
    float* __restrict__ Sbuf)
{
    const int bx = blockIdx.x;
    const int c  = bx >> 8;
    const int j  = bx & 255;
    const int b  = j >> 6;
    const int e0 = (j & 63) << 4;
    const int tid = threadIdx.x;
    const int g = tid >> 4;
    const int n = tid & 15;
    const int e = e0 + g;
    const int srow = tid >> 2;
    const int sc4  = (tid & 3) * 4;

    __shared__ float sDt[64][20];
    __shared__ float sU[64][20];

    const float A_n = -__expf(Alog[(size_t)e * Ns + n]);
    float h = 0.f, Pa = 1.f;

    const unsigned short* uT = xcT + (size_t)b * Lc * Ei;
    const unsigned short* dT = dt16 + (size_t)b * Lc * Ei;
    const float* xdb = xdbl + (size_t)b * 64 * Lc;
    const float* Brow = &xdb[(size_t)(32 + n) * Lc];

    const int tbeg = c * TCH;
    for (int t0 = tbeg; t0 < tbeg + TCH; t0 += 64) {
        ushort4 uu = *(const ushort4*)&uT[(size_t)(t0 + srow) * Ei + e0 + sc4];
        ushort4 dd = *(const ushort4*)&dT[(size_t)(t0 + srow) * Ei + e0 + sc4];
        *(float4*)&sU[srow][sc4]  = make_float4(bf2f(uu.x), bf2f(uu.y), bf2f(uu.z), bf2f(uu.w));
        *(float4*)&sDt[srow][sc4] = make_float4(bf2f(dd.x), bf2f(dd.y), bf2f(dd.z), bf2f(dd.w));
        __syncthreads();
#pragma unroll
        for (int s = 0; s < 4; s++) {
            float bArr[16];
#pragma unroll
            for (int k = 0; k < 4; k++) {
                float4 bq = *(const float4*)&Brow[t0 + s * 16 + k * 4];
                bArr[k * 4 + 0] = bq.x; bArr[k * 4 + 1] = bq.y;
                bArr[k * 4 + 2] = bq.z; bArr[k * 4 + 3] = bq.w;
            }
#pragma unroll
            for (int t2 = 0; t2 < 16; t2++) {
                int tt = s * 16 + t2;
                float dt = sDt[tt][g];
                float dA = __expf(dt * A_n);
                h  = fmaf(dA, h, dt * sU[tt][g] * bArr[t2]);
                Pa *= dA;
            }
        }
        __syncthreads();
    }
    size_t idx = ((size_t)(c * 4 + b) * 1024 + e) * 16 + n;
    Pbuf[idx] = Pa;
    Sbuf[idx] = h;
}

// ---------------------------------------------------------------------------
// K5c: scan pass 2 — per-block h_in composition (mid kernel folded in),
// replay chunk, y via sP-transpose reduce, gated bf16 output via sY tile.
// LDS 34.5KB -> 4 blocks/CU.
// ---------------------------------------------------------------------------
__global__ __launch_bounds__(256, 4) void k_scan_p2(
    const unsigned short* __restrict__ xcT,   // u bf16 [b][t][e]
    const float* __restrict__ xdbl,
    const unsigned short* __restrict__ xz,    // bf16; z rows Ei..2Ei-1
    const unsigned short* __restrict__ dt16,  // bf16 [b][t][e]
    const float* __restrict__ Alog,
    const float* __restrict__ Dp,
    const float* __restrict__ Pbuf,    // [NCH][4][1024][16]
    const float* __restrict__ Sbuf,
    unsigned short* __restrict__ ybf,  // (4,2048,1024) bf16
    int rev)
{
    const int bx = blockIdx.x;
    const int c  = bx >> 8;
    const int j  = bx & 255;
    const int b  = j >> 6;
    const int e0 = (j & 63) << 4;
    const int tid = threadIdx.x;
    const int g = tid >> 4;
    const int n = tid & 15;
    const int e = e0 + g;
    const int srow = tid >> 2;
    const int sc4  = (tid & 3) * 4;

    __shared__ float sDt[64][20];
    __shared__ float sU[64][20];
    __shared__ float sP[16][17][20];
    __shared__ unsigned short sY[64][20];

    const float A_n = -__expf(Alog[(size_t)e * Ns + n]);
    const float Dv  = Dp[e];

    // fold-in of the mid kernel: compose h_in from chunks 0..c-1
    float h = 0.f;
    for (int cc = 0; cc < c; cc++) {
        size_t pidx = ((size_t)(cc * 4 + b) * 1024 + e) * 16 + n;
        h = Sbuf[pidx] + Pbuf[pidx] * h;
    }

    const unsigned short* uT = xcT + (size_t)b * Lc * Ei;
    const unsigned short* dT = dt16 + (size_t)b * Lc * Ei;
    const unsigned short* zp = xz + ((size_t)b * 2048 + Ei + e) * Lc;
    const float* xdb = xdbl + (size_t)b * 64 * Lc;
    const float* Brow = &xdb[(size_t)(32 + n) * Lc];
    const float* Crow = &xdb[(size_t)(48 + n) * Lc];

    const int tbeg = c * TCH;
    for (int t0 = tbeg; t0 < tbeg + TCH; t0 += 64) {
        ushort4 uu = *(const ushort4*)&uT[(size_t)(t0 + srow) * Ei + e0 + sc4];
        ushort4 dd = *(const ushort4*)&dT[(size_t)(t0 + srow) * Ei + e0 + sc4];
        *(float4*)&sU[srow][sc4]  = make_float4(bf2f(uu.x), bf2f(uu.y), bf2f(uu.z), bf2f(uu.w));
        *(float4*)&sDt[srow][sc4] = make_float4(bf2f(dd.x), bf2f(dd.y), bf2f(dd.z), bf2f(dd.w));
        __syncthreads();

#pragma unroll
        for (int s = 0; s < 4; s++) {
            float bArr[16], cArr[16];
#pragma unroll
            for (int k = 0; k < 4; k++) {
                float4 bq = *(const float4*)&Brow[t0 + s * 16 + k * 4];
                float4 cq = *(const float4*)&Crow[t0 + s * 16 + k * 4];
                bArr[k * 4 + 0] = bq.x; bArr[k * 4 + 1] = bq.y;
                bArr[k * 4 + 2] = bq.z; bArr[k * 4 + 3] = bq.w;
                cArr[k * 4 + 0] = cq.x; cArr[k * 4 + 1] = cq.y;
                cArr[k * 4 + 2] = cq.z; cArr[k * 4 + 3] = cq.w;
            }
#pragma unroll
            for (int t2 = 0; t2 < 16; t2++) {
                int tt = s * 16 + t2;
                float dt = sDt[tt][g];
                float dA = __expf(dt * A_n);
                h = fmaf(dA, h, dt * sU[tt][g] * bArr[t2]);
                sP[g][t2][n] = h * cArr[t2];
            }
            // same-wave transposed reduce: lane (g,n) sums states for tt=s*16+n
            float4 p0 = *(float4*)&sP[g][n][0];
            float4 p1 = *(float4*)&sP[g][n][4];
            float4 p2 = *(float4*)&sP[g][n][8];
            float4 p3 = *(float4*)&sP[g][n][12];
            float acc = ((p0.x + p0.y) + (p0.z + p0.w)) + ((p1.x + p1.y) + (p1.z + p1.w)) +
                        ((p2.x + p2.y) + (p2.z + p2.w)) + ((p3.x + p3.y) + (p3.z + p3.w));
            int tt = s * 16 + n;
            int t  = t0 + tt;
            int gi = rev ? (Lc - 1 - t) : t;
            float val = (acc + Dv * sU[tt][g]) * siluf(bf2f(zp[gi]));
            sY[rev ? (63 - tt) : tt][g] = f2bf(val);
        }
        __syncthreads();

        // coalesced tile write: rows are contiguous t (fwd) or reversed range
        {
            int trow = rev ? (Lc - 64 - t0 + srow) : (t0 + srow);
            size_t gidx = ((size_t)b * Lc + trow) * Ei + e0 + sc4;
            ushort4 tv = *(ushort4*)&sY[srow][sc4];
            if (rev) {
                ushort4 ov = *(ushort4*)&ybf[gidx];
                tv.x = f2bf(bf2f(tv.x) + bf2f(ov.x));
                tv.y = f2bf(bf2f(tv.y) + bf2f(ov.y));
                tv.z = f2bf(bf2f(tv.z) + bf2f(ov.z));
                tv.w = f2bf(bf2f(tv.w) + bf2f(ov.w));
            }
            *(ushort4*)&ybf[gidx] = tv;
        }
        __syncthreads();
    }
}

// ---------------------------------------------------------------------------
// K6: out_proj bf16 MFMA GEMM. out[b][n][m] = sum_e Wout[m][e]*ybf[b][n][e]
// ---------------------------------------------------------------------------
__global__ __launch_bounds__(256) void k_mfma_outproj(
    const unsigned short* __restrict__ Wbf,  // (512,1024) bf16
    const unsigned short* __restrict__ ybf,  // (4,2048,1024) bf16
    float* __restrict__ out)                 // (4,2048,512)
{
    const int b  = blockIdx.z;
    const int m0 = blockIdx.x * 64;
    const int n0 = blockIdx.y * 128;
    __shared__ __align__(16) unsigned short lA[64 * LDS_S];
    __shared__ __align__(16) unsigned short lB[128 * LDS_S];
    const int tid  = threadIdx.x;
    const int lane = tid & 63;
    const int w    = tid >> 6;
    const int wr   = w >> 1, wc = w & 1;

    f32x4 acc[2][4] = {};

    const unsigned short* yb = ybf + ((size_t)b * Lc + n0) * Ei;
    const unsigned short* Wb = Wbf + (size_t)m0 * Ei;

    for (int k0 = 0; k0 < Ei; k0 += 32) {
        {
            int c = tid;
            int row = c >> 2, col = (c & 3) * 8;
            *(uint4*)&lA[row * LDS_S + col] = *(const uint4*)&Wb[(size_t)row * Ei + k0 + col];
        }
#pragma unroll
        for (int i = 0; i < 2; i++) {
            int c = tid + i * 256;
            int row = c >> 2, col = (c & 3) * 8;
            *(uint4*)&lB[row * LDS_S + col] = *(const uint4*)&yb[(size_t)row * Ei + k0 + col];
        }
        __syncthreads();
        bf16x8 aF[2], bF[4];
#pragma unroll
        for (int f = 0; f < 2; f++)
            aF[f] = *(bf16x8*)&lA[(wr * 32 + f * 16 + (lane & 15)) * LDS_S + (lane >> 4) * 8];
#pragma unroll
        for (int f = 0; f < 4; f++)
            bF[f] = *(bf16x8*)&lB[(wc * 64 + f * 16 + (lane & 15)) * LDS_S + (lane >> 4) * 8];
#pragma unroll
        for (int i = 0; i < 2; i++)
#pragma unroll
            for (int j = 0; j < 4; j++)
                acc[i][j] = __builtin_amdgcn_mfma_f32_16x16x32_bf16(aF[i], bF[j], acc[i][j], 0, 0, 0);
        __syncthreads();
    }
    float* ob = out + (size_t)b * Lc * Dm;
#pragma unroll
    for (int i = 0; i < 2; i++) {
        int mm = m0 + wr * 32 + i * 16 + (lane >> 4) * 4;
#pragma unroll
        for (int j = 0; j < 4; j++) {
            int nn = n0 + wc * 64 + j * 16 + (lane & 15);
            *(f32x4*)&ob[(size_t)nn * Dm + mm] = acc[i][j];
        }
    }
}

// ---------------------------------------------------------------------------
// K7: fused residual add + RMSNorm (in place on d_out).
// ---------------------------------------------------------------------------
__global__ __launch_bounds__(256) void k_rms(float* __restrict__ out,
                                             const float* __restrict__ resid,
                                             const float* __restrict__ w) {
    int row  = blockIdx.x * 4 + (threadIdx.x >> 6);
    int lane = threadIdx.x & 63;
    float4* po = (float4*)(out + (size_t)row * Dm);
    const float4* pr = (const float4*)(resid + (size_t)row * Dm);
    const float4* pw = (const float4*)w;
    float4 a0 = po[lane], a1 = po[lane + 64];
    float4 r0 = pr[lane], r1 = pr[lane + 64];
    a0.x += r0.x; a0.y += r0.y; a0.z += r0.z; a0.w += r0.w;
    a1.x += r1.x; a1.y += r1.y; a1.z += r1.z; a1.w += r1.w;
    float q = a0.x * a0.x + a0.y * a0.y + a0.z * a0.z + a0.w * a0.w +
              a1.x * a1.x + a1.y * a1.y + a1.z * a1.z + a1.w * a1.w;
#pragma unroll
    for (int off = 32; off >= 1; off >>= 1) q += __shfl_xor(q, off);
    float scale = rsqrtf(q * (1.f / Dm) + EPSf);
    float4 w0 = pw[lane], w1 = pw[lane + 64];
    a0.x *= scale * w0.x; a0.y *= scale * w0.y; a0.z *= scale * w0.z; a0.w *= scale * w0.w;
    a1.x *= scale * w1.x; a1.y *= scale * w1.y; a1.z *= scale * w1.z; a1.w *= scale * w1.w;
    po[lane] = a0;
    po[lane + 64] = a1;
}

// ---------------------------------------------------------------------------
extern "C" void kernel_launch(void* const* d_in, const int* in_sizes, int n_in,
                              void* d_out, int out_size, void* d_ws, size_t ws_size,
                              hipStream_t stream) {
    const float* inp   = (const float*)d_in[0];
    const float* nw    = (const float*)d_in[1];
    const float* nbv   = (const float*)d_in[2];
    const float* Win   = (const float*)d_in[3];
    const float* cwf   = (const float*)d_in[4];
    const float* cbf   = (const float*)d_in[5];
    const float* xpwf  = (const float*)d_in[6];
    const float* dtwf  = (const float*)d_in[7];
    const float* dtbf  = (const float*)d_in[8];
    const float* Alogf = (const float*)d_in[9];
    const float* Df    = (const float*)d_in[10];
    const float* cwr   = (const float*)d_in[11];
    const float* cbr   = (const float*)d_in[12];
    const float* xpwr  = (const float*)d_in[13];
    const float* dtwr  = (const float*)d_in[14];
    const float* dtbr  = (const float*)d_in[15];
    const float* Alogr = (const float*)d_in[16];
    const float* Dr    = (const float*)d_in[17];
    const float* Wout  = (const float*)d_in[18];
    const float* nfw   = (const float*)d_in[19];
    float* outp = (float*)d_out;

    // workspace layout
    unsigned short* xz   = (unsigned short*)d_ws;        // 16,777,216 us (bf16)
    float* xdbl = (float*)(xz + (size_t)16777216);       //    524,288 f
    unsigned short* xcT = (unsigned short*)(xdbl + 524288); // 8,388,608 us
    unsigned short* ybf = xcT + (size_t)8388608;             // 8,388,608 us
    unsigned short* hbf = ybf + (size_t)8388608;             // 4,194,304 us
    unsigned short* wbi = hbf + (size_t)4194304;             // 1,048,576 us
    unsigned short* wbo = wbi + (size_t)1048576;             //   524,288 us
    unsigned short* dt16 = wbo + (size_t)524288;             // 8,388,608 us
    unsigned short* xpbf = dt16 + (size_t)8388608;           //    65,536 us
    unsigned short* xpbr = xpbf + (size_t)65536;             //    65,536 us

    // P/S scratch lives in d_out (4.19M floats; overwritten by out_proj at
    // the end). Each buffer NCH*4*1024*16 = 1,048,576 floats.
    float* Pb = outp;
    float* Sb = outp + 1048576;

    k_ln<<<2048, 256, 0, stream>>>(inp, nw, nbv, hbf);
    k_castall<<<1664, 256, 0, stream>>>(Win, wbi, Wout, wbo, xpwf, xpbf, xpwr, xpbr);
    k_mfma_inproj<<<dim3(16, 16, 4), 256, 0, stream>>>(wbi, hbf, xz);

    // forward branch
    k_conv<<<dim3(32, 64, 4), 256, 0, stream>>>(xz, cwf, cbf, xcT, 0);
    k_mfma_xdbl<<<dim3(16, 4), 256, 0, stream>>>(xpbf, xcT, xdbl);
    k_dt<<<dim3(32, 64, 4), 256, 0, stream>>>(xdbl, dtwf, dtbf, dt16);
    k_scan_p1<<<NCH * 256, 256, 0, stream>>>(xcT, xdbl, dt16, Alogf, Pb, Sb);
    k_scan_p2<<<NCH * 256, 256, 0, stream>>>(xcT, xdbl, xz, dt16, Alogf, Df, Pb, Sb, ybf, 0);

    // reverse branch (index-reversed, accumulates into ybf)
    k_conv<<<dim3(32, 64, 4), 256, 0, stream>>>(xz, cwr, cbr, xcT, 1);
    k_mfma_xdbl<<<dim3(16, 4), 256, 0, stream>>>(xpbr, xcT, xdbl);
    k_dt<<<dim3(32, 64, 4), 256, 0, stream>>>(xdbl, dtwr, dtbr, dt16);
    k_scan_p1<<<NCH * 256, 256, 0, stream>>>(xcT, xdbl, dt16, Alogr, Pb, Sb);
    k_scan_p2<<<NCH * 256, 256, 0, stream>>>(xcT, xdbl, xz, dt16, Alogr, Dr, Pb, Sb, ybf, 1);

    k_mfma_outproj<<<dim3(8, 16, 4), 256, 0, stream>>>(wbo, ybf, outp);
    k_rms<<<2048, 256, 0, stream>>>(outp, inp, nfw);
}

// Round 8
// 439.404 us; speedup vs baseline: 1.4194x; 1.4194x over previous
//
#include <hip/hip_runtime.h>
#include <math.h>
#include <stdint.h>

// Problem constants
#define Bb 4
#define Lc 2048
#define Dm 512
#define Ei 1024     // E = 2*D_MODEL
#define Ns 16       // d_state
#define Rr 32       // dt_rank
#define EPSf 1e-5f
#define NCH 16      // scan chunks
#define TCH 128     // timesteps per chunk
#define LDS_S 40    // padded LDS row stride (ushorts) for MFMA tiles

typedef __attribute__((ext_vector_type(8))) short bf16x8;
typedef __attribute__((ext_vector_type(4))) float f32x4;

__device__ __forceinline__ float siluf(float x) {
    return x / (1.f + __expf(-x));
}
__device__ __forceinline__ float softplusf(float x) {
    return x > 20.f ? x : log1pf(__expf(x));
}
__device__ __forceinline__ unsigned short f2bf(float x) {
    union { float f; unsigned u; } v; v.f = x;
    unsigned r = (v.u + 0x7FFFu + ((v.u >> 16) & 1u)) >> 16;
    return (unsigned short)r;
}
__device__ __forceinline__ float bf2f(unsigned short x) {
    union { unsigned u; float f; } v; v.u = ((unsigned)x) << 16;
    return v.f;
}

// ---------------------------------------------------------------------------
// K1: LayerNorm -> bf16 h. One wave per row (D=512), 4 rows/block.
// ---------------------------------------------------------------------------
__global__ __launch_bounds__(256) void k_ln(const float* __restrict__ inp,
                                            const float* __restrict__ nw,
                                            const float* __restrict__ nb,
                                            unsigned short* __restrict__ hbf) {
    int row  = blockIdx.x * 4 + (threadIdx.x >> 6);
    int lane = threadIdx.x & 63;
    const float4* p = (const float4*)(inp + (size_t)row * Dm);
    float4 v0 = p[lane];
    float4 v1 = p[lane + 64];
    float s = v0.x + v0.y + v0.z + v0.w + v1.x + v1.y + v1.z + v1.w;
    float q = v0.x * v0.x + v0.y * v0.y + v0.z * v0.z + v0.w * v0.w +
              v1.x * v1.x + v1.y * v1.y + v1.z * v1.z + v1.w * v1.w;
#pragma unroll
    for (int off = 32; off >= 1; off >>= 1) {
        s += __shfl_xor(s, off);
        q += __shfl_xor(q, off);
    }
    float mu = s * (1.f / Dm);
    float rs = rsqrtf(q * (1.f / Dm) - mu * mu + EPSf);
    int d0 = lane * 4, d1 = 256 + lane * 4;
    float4 w0 = *(const float4*)&nw[d0], w1 = *(const float4*)&nw[d1];
    float4 b0 = *(const float4*)&nb[d0], b1 = *(const float4*)&nb[d1];
    ushort4 o0, o1;
    o0.x = f2bf((v0.x - mu) * rs * w0.x + b0.x);
    o0.y = f2bf((v0.y - mu) * rs * w0.y + b0.y);
    o0.z = f2bf((v0.z - mu) * rs * w0.z + b0.z);
    o0.w = f2bf((v0.w - mu) * rs * w0.w + b0.w);
    o1.x = f2bf((v1.x - mu) * rs * w1.x + b1.x);
    o1.y = f2bf((v1.y - mu) * rs * w1.y + b1.y);
    o1.z = f2bf((v1.z - mu) * rs * w1.z + b1.z);
    o1.w = f2bf((v1.w - mu) * rs * w1.w + b1.w);
    *(ushort4*)&hbf[(size_t)row * Dm + d0] = o0;
    *(ushort4*)&hbf[(size_t)row * Dm + d1] = o1;
}

// ---------------------------------------------------------------------------
// K1b: merged fp32 -> bf16 cast of all four weight tensors. Quad-indexed.
// ---------------------------------------------------------------------------
__global__ __launch_bounds__(256) void k_castall(
    const float* __restrict__ Win,  unsigned short* __restrict__ wbi,
    const float* __restrict__ Wout, unsigned short* __restrict__ wbo,
    const float* __restrict__ xpf,  unsigned short* __restrict__ xpbf,
    const float* __restrict__ xpr,  unsigned short* __restrict__ xpbr) {
    size_t q = (size_t)blockIdx.x * 256 + threadIdx.x;  // quad index
    const float* src; unsigned short* dst; size_t off;
    if (q < 262144)      { src = Win;  dst = wbi;  off = q; }
    else if (q < 393216) { src = Wout; dst = wbo;  off = q - 262144; }
    else if (q < 409600) { src = xpf;  dst = xpbf; off = q - 393216; }
    else                 { src = xpr;  dst = xpbr; off = q - 409600; }
    float4 v = ((const float4*)src)[off];
    ushort4 o;
    o.x = f2bf(v.x); o.y = f2bf(v.y); o.z = f2bf(v.z); o.w = f2bf(v.w);
    ((ushort4*)dst)[off] = o;
}

// ---------------------------------------------------------------------------
// K2: in_proj bf16 MFMA GEMM.  xz[b][m][n] = sum_k W[m][k] * h[b*L+n][k]
// ---------------------------------------------------------------------------
__global__ __launch_bounds__(256) void k_mfma_inproj(
    const unsigned short* __restrict__ Wbf,  // (2048,512) bf16
    const unsigned short* __restrict__ hbf,  // (8192,512) bf16
    unsigned short* __restrict__ xz)         // (4,2048,2048) bf16
{
    const int b  = blockIdx.z;
    const int m0 = blockIdx.x * 128;
    const int n0 = blockIdx.y * 128;
    __shared__ __align__(16) unsigned short lA[128 * LDS_S];
    __shared__ __align__(16) unsigned short lB[128 * LDS_S];
    const int tid  = threadIdx.x;
    const int lane = tid & 63;
    const int w    = tid >> 6;
    const int wr   = w >> 1, wc = w & 1;

    f32x4 acc[4][4] = {};

    const unsigned short* hb = hbf + ((size_t)b * Lc + n0) * Dm;
    const unsigned short* Wb = Wbf + (size_t)m0 * Dm;

    for (int k0 = 0; k0 < Dm; k0 += 32) {
#pragma unroll
        for (int i = 0; i < 2; i++) {
            int c = tid + i * 256;            // 512 16B-chunks per tile
            int row = c >> 2, col = (c & 3) * 8;
            *(uint4*)&lA[row * LDS_S + col] = *(const uint4*)&Wb[(size_t)row * Dm + k0 + col];
            *(uint4*)&lB[row * LDS_S + col] = *(const uint4*)&hb[(size_t)row * Dm + k0 + col];
        }
        __syncthreads();
        bf16x8 aF[4], bF[4];
#pragma unroll
        for (int f = 0; f < 4; f++) {
            aF[f] = *(bf16x8*)&lA[(wr * 64 + f * 16 + (lane & 15)) * LDS_S + (lane >> 4) * 8];
            bF[f] = *(bf16x8*)&lB[(wc * 64 + f * 16 + (lane & 15)) * LDS_S + (lane >> 4) * 8];
        }
#pragma unroll
        for (int i = 0; i < 4; i++)
#pragma unroll
            for (int j = 0; j < 4; j++)
                acc[i][j] = __builtin_amdgcn_mfma_f32_16x16x32_bf16(aF[i], bF[j], acc[i][j], 0, 0, 0);
        __syncthreads();
    }
    unsigned short* Cb = xz + (size_t)b * 2048 * Lc;
#pragma unroll
    for (int i = 0; i < 4; i++) {
        int mbase = m0 + wr * 64 + i * 16 + (lane >> 4) * 4;
#pragma unroll
        for (int j = 0; j < 4; j++) {
            int nn = n0 + wc * 64 + j * 16 + (lane & 15);
#pragma unroll
            for (int r = 0; r < 4; r++)
                Cb[(size_t)(mbase + r) * Lc + nn] = f2bf(acc[i][j][r]);
        }
    }
}

// ---------------------------------------------------------------------------
// K3: tiled causal depthwise conv (K=4) + SiLU on bf16 xz.
// Emits xcT [b][L][e] bf16 via LDS transpose tile.
// ---------------------------------------------------------------------------
__global__ __launch_bounds__(256) void k_conv(const unsigned short* __restrict__ xz,
                                              const float* __restrict__ cw,
                                              const float* __restrict__ cb,
                                              unsigned short* __restrict__ xcT,
                                              int rev) {
    const int b  = blockIdx.z;
    const int e0 = blockIdx.y * 16;
    const int t0 = blockIdx.x * 64;
    const int tid = threadIdx.x;
    const int g = tid >> 4;
    const int n = tid & 15;
    const int e = e0 + g;
    const int j0 = t0 + n * 4;

    __shared__ unsigned short sY[64][20];   // stride 40 B: ushort4-aligned rows

    const unsigned short* x = xz + ((size_t)b * 2048 + e) * Lc;
    float w0 = cw[e * 4], w1 = cw[e * 4 + 1], w2 = cw[e * 4 + 2], w3 = cw[e * 4 + 3];
    float bias = cb[e];

    float v[8];  // xin[j0-4 .. j0+3] (xin = x or reversed x)
    if (!rev) {
        ushort4 cur = *(const ushort4*)&x[j0];
        v[4] = bf2f(cur.x); v[5] = bf2f(cur.y); v[6] = bf2f(cur.z); v[7] = bf2f(cur.w);
        if (j0 >= 4) {
            ushort4 prv = *(const ushort4*)&x[j0 - 4];
            v[0] = bf2f(prv.x); v[1] = bf2f(prv.y); v[2] = bf2f(prv.z); v[3] = bf2f(prv.w);
        } else { v[0] = v[1] = v[2] = v[3] = 0.f; }
    } else {
        ushort4 c4 = *(const ushort4*)&x[Lc - 4 - j0];
        v[4] = bf2f(c4.w); v[5] = bf2f(c4.z); v[6] = bf2f(c4.y); v[7] = bf2f(c4.x);
        if (j0 >= 4) {
            ushort4 p4 = *(const ushort4*)&x[Lc - j0];
            v[0] = bf2f(p4.w); v[1] = bf2f(p4.z); v[2] = bf2f(p4.y); v[3] = bf2f(p4.x);
        } else { v[0] = v[1] = v[2] = v[3] = 0.f; }
    }

#pragma unroll
    for (int jj = 0; jj < 4; jj++) {
        float a = bias + w0 * v[jj + 1] + w1 * v[jj + 2] + w2 * v[jj + 3] + w3 * v[jj + 4];
        sY[n * 4 + jj][g] = f2bf(siluf(a));
    }
    __syncthreads();

    int row = tid >> 2;
    int c4  = (tid & 3) * 4;
    ushort4 tv = *(ushort4*)&sY[row][c4];
    *(ushort4*)&xcT[((size_t)b * Lc + t0 + row) * Ei + e0 + c4] = tv;
}

// ---------------------------------------------------------------------------
// K4: x_proj bf16 MFMA GEMM: xdbl[b][m][n] = sum_e xpw[m][e] * xcT[b][n][e]
// Output bf16 (halves dt/scan staging traffic).
// ---------------------------------------------------------------------------
__global__ __launch_bounds__(256) void k_mfma_xdbl(
    const unsigned short* __restrict__ xpb,  // (64,1024) bf16
    const unsigned short* __restrict__ xcT,  // (4,2048,1024) bf16
    unsigned short* __restrict__ xdbl)       // (4,64,2048) bf16
{
    const int n0 = blockIdx.x * 128;
    const int b  = blockIdx.y;
    __shared__ __align__(16) unsigned short lA[64 * LDS_S];
    __shared__ __align__(16) unsigned short lB[128 * LDS_S];
    const int tid  = threadIdx.x;
    const int lane = tid & 63;
    const int w    = tid >> 6;

    f32x4 acc[4][2] = {};

    const unsigned short* yb = xcT + ((size_t)b * Lc + n0) * Ei;

    for (int k0 = 0; k0 < Ei; k0 += 32) {
        {
            int c = tid;
            int row = c >> 2, col = (c & 3) * 8;
            *(uint4*)&lA[row * LDS_S + col] = *(const uint4*)&xpb[(size_t)row * Ei + k0 + col];
        }
#pragma unroll
        for (int i = 0; i < 2; i++) {
            int c = tid + i * 256;
            int row = c >> 2, col = (c & 3) * 8;
            *(uint4*)&lB[row * LDS_S + col] = *(const uint4*)&yb[(size_t)row * Ei + k0 + col];
        }
        __syncthreads();
        bf16x8 aF[4], bF[2];
#pragma unroll
        for (int f = 0; f < 4; f++)
            aF[f] = *(bf16x8*)&lA[(f * 16 + (lane & 15)) * LDS_S + (lane >> 4) * 8];
#pragma unroll
        for (int f = 0; f < 2; f++)
            bF[f] = *(bf16x8*)&lB[(w * 32 + f * 16 + (lane & 15)) * LDS_S + (lane >> 4) * 8];
#pragma unroll
        for (int i = 0; i < 4; i++)
#pragma unroll
            for (int j = 0; j < 2; j++)
                acc[i][j] = __builtin_amdgcn_mfma_f32_16x16x32_bf16(aF[i], bF[j], acc[i][j], 0, 0, 0);
        __syncthreads();
    }
    unsigned short* xd = xdbl + (size_t)b * 64 * Lc;
#pragma unroll
    for (int i = 0; i < 4; i++) {
        int mbase = i * 16 + (lane >> 4) * 4;
#pragma unroll
        for (int j = 0; j < 2; j++) {
            int nn = n0 + w * 32 + j * 16 + (lane & 15);
#pragma unroll
            for (int r = 0; r < 4; r++)
                xd[(size_t)(mbase + r) * Lc + nn] = f2bf(acc[i][j][r]);
        }
    }
}

// ---------------------------------------------------------------------------
// K4b: dt = softplus(dtw @ dt_low + bias).  xdbl now bf16. Output bf16
// [b][t][e] via LDS transpose tile.  Block: 16 e x 64 t.
// ---------------------------------------------------------------------------
__global__ __launch_bounds__(256) void k_dt(
    const unsigned short* __restrict__ xdbl, // (4,64,2048) bf16; rows 0..31 dt_low
    const float* __restrict__ dtw,   // (1024,32)
    const float* __restrict__ dtb,   // (1024)
    unsigned short* __restrict__ dt16) // (4,2048,1024) bf16 [t][e]
{
    const int b  = blockIdx.z;
    const int e0 = blockIdx.y * 16;
    const int t0 = blockIdx.x * 64;
    const int tid = threadIdx.x;
    const int g = tid >> 4;          // local e
    const int n = tid & 15;          // t-quad selector
    const int e = e0 + g;

    __shared__ float sW[16][33];
    __shared__ float sDtl[32][68];
    __shared__ unsigned short sT[64][20];

    for (int i = tid; i < 512; i += 256)
        sW[i >> 5][i & 31] = dtw[(size_t)(e0 + (i >> 5)) * 32 + (i & 31)];

    const unsigned short* xdb = xdbl + (size_t)b * 64 * Lc;
#pragma unroll
    for (int f = 0; f < 2; f++) {
        int fi = tid * 2 + f;            // 512 quad slots (32 rows x 16 quads)
        int row = fi >> 4, c4 = (fi & 15) * 4;
        ushort4 q = *(const ushort4*)&xdb[(size_t)row * Lc + t0 + c4];
        *(float4*)&sDtl[row][c4] = make_float4(bf2f(q.x), bf2f(q.y), bf2f(q.z), bf2f(q.w));
    }
    __syncthreads();

    const float bias = dtb[e];
#pragma unroll
    for (int jj = 0; jj < 4; jj++) {
        int tt = n * 4 + jj;
        float a = bias;
#pragma unroll
        for (int r = 0; r < 32; r++) a += sDtl[r][tt] * sW[g][r];
        sT[tt][g] = f2bf(softplusf(a));
    }
    __syncthreads();

    int row = tid >> 2;
    int c4  = (tid & 3) * 4;
    ushort4 tv = *(ushort4*)&sT[row][c4];
    *(ushort4*)&dt16[((size_t)b * Lc + t0 + row) * Ei + e0 + c4] = tv;
}

// ---------------------------------------------------------------------------
// K5a: scan pass 1 — per-chunk affine transform (P = prod dA, S = local h).
// u/dt tile-staged from [t][e]; B COALESCED-staged to LDS (R6 pattern).
// ---------------------------------------------------------------------------
__global__ __launch_bounds__(256) void k_scan_p1(
    const unsigned short* __restrict__ xcT,   // u bf16 [b][t][e]
    const unsigned short* __restrict__ xdbl,  // bf16 (4,64,2048)
    const unsigned short* __restrict__ dt16,  // bf16 [b][t][e]
    const float* __restrict__ Alog,
    float* __restrict__ Pbuf,          // [NCH][4][1024][16]
    float* __restrict__ Sbuf)
{
    const int bx = blockIdx.x;
    const int c  = bx >> 8;
    const int j  = bx & 255;
    const int b  = j >> 6;
    const int e0 = (j & 63) << 4;
    const int tid = threadIdx.x;
    const int g = tid >> 4;
    const int n = tid & 15;
    const int e = e0 + g;
    const int srow = tid >> 2;
    const int sc4  = (tid & 3) * 4;

    __shared__ float sDt[64][20];
    __shared__ float sU[64][20];
    __shared__ float sB[16][68];

    const float A_n = -__expf(Alog[(size_t)e * Ns + n]);
    float h = 0.f, Pa = 1.f;

    const unsigned short* uT = xcT + (size_t)b * Lc * Ei;
    const unsigned short* dT = dt16 + (size_t)b * Lc * Ei;
    const unsigned short* xdb = xdbl + (size_t)b * 64 * Lc;

    const int tbeg = c * TCH;
    for (int t0 = tbeg; t0 < tbeg + TCH; t0 += 64) {
        ushort4 uu = *(const ushort4*)&uT[(size_t)(t0 + srow) * Ei + e0 + sc4];
        ushort4 dd = *(const ushort4*)&dT[(size_t)(t0 + srow) * Ei + e0 + sc4];
        *(float4*)&sU[srow][sc4]  = make_float4(bf2f(uu.x), bf2f(uu.y), bf2f(uu.z), bf2f(uu.w));
        *(float4*)&sDt[srow][sc4] = make_float4(bf2f(dd.x), bf2f(dd.y), bf2f(dd.z), bf2f(dd.w));
        {   // B row stage: lane (g,n) reads row 32+g, cols t0+n*4 (coalesced)
            ushort4 bb = *(const ushort4*)&xdb[(size_t)(32 + g) * Lc + t0 + n * 4];
            *(float4*)&sB[g][n * 4] = make_float4(bf2f(bb.x), bf2f(bb.y), bf2f(bb.z), bf2f(bb.w));
        }
        __syncthreads();
#pragma unroll
        for (int tt = 0; tt < 64; tt++) {
            float dt = sDt[tt][g];
            float dA = __expf(dt * A_n);
            h  = fmaf(dA, h, dt * sU[tt][g] * sB[n][tt]);
            Pa *= dA;
        }
        __syncthreads();
    }
    size_t idx = ((size_t)(c * 4 + b) * 1024 + e) * 16 + n;
    Pbuf[idx] = Pa;
    Sbuf[idx] = h;
}

// ---------------------------------------------------------------------------
// K5c: scan pass 2 — per-block h_in composition, replay chunk, y via
// sP-transpose reduce, gated bf16 output via sY tile. B/C LDS-staged
// coalesced (the R7 register-path regression is reverted).
// ---------------------------------------------------------------------------
__global__ __launch_bounds__(256) void k_scan_p2(
    const unsigned short* __restrict__ xcT,   // u bf16 [b][t][e]
    const unsigned short* __restrict__ xdbl,  // bf16 (4,64,2048)
    const unsigned short* __restrict__ xz,    // bf16; z rows Ei..2Ei-1
    const unsigned short* __restrict__ dt16,  // bf16 [b][t][e]
    const float* __restrict__ Alog,
    const float* __restrict__ Dp,
    const float* __restrict__ Pbuf,    // [NCH][4][1024][16]
    const float* __restrict__ Sbuf,
    unsigned short* __restrict__ ybf,  // (4,2048,1024) bf16
    int rev)
{
    const int bx = blockIdx.x;
    const int c  = bx >> 8;
    const int j  = bx & 255;
    const int b  = j >> 6;
    const int e0 = (j & 63) << 4;
    const int tid = threadIdx.x;
    const int g = tid >> 4;
    const int n = tid & 15;
    const int e = e0 + g;
    const int srow = tid >> 2;
    const int sc4  = (tid & 3) * 4;

    __shared__ float sDt[64][20];
    __shared__ float sU[64][20];
    __shared__ float sB[16][68];
    __shared__ float sC[16][68];
    __shared__ float sP[16][17][20];
    __shared__ unsigned short sY[64][20];

    const float A_n = -__expf(Alog[(size_t)e * Ns + n]);
    const float Dv  = Dp[e];

    // folded mid kernel: compose h_in from chunks 0..c-1
    float h = 0.f;
    for (int cc = 0; cc < c; cc++) {
        size_t pidx = ((size_t)(cc * 4 + b) * 1024 + e) * 16 + n;
        h = Sbuf[pidx] + Pbuf[pidx] * h;
    }

    const unsigned short* uT = xcT + (size_t)b * Lc * Ei;
    const unsigned short* dT = dt16 + (size_t)b * Lc * Ei;
    const unsigned short* zp = xz + ((size_t)b * 2048 + Ei + e) * Lc;
    const unsigned short* xdb = xdbl + (size_t)b * 64 * Lc;

    const int tbeg = c * TCH;
    for (int t0 = tbeg; t0 < tbeg + TCH; t0 += 64) {
        ushort4 uu = *(const ushort4*)&uT[(size_t)(t0 + srow) * Ei + e0 + sc4];
        ushort4 dd = *(const ushort4*)&dT[(size_t)(t0 + srow) * Ei + e0 + sc4];
        *(float4*)&sU[srow][sc4]  = make_float4(bf2f(uu.x), bf2f(uu.y), bf2f(uu.z), bf2f(uu.w));
        *(float4*)&sDt[srow][sc4] = make_float4(bf2f(dd.x), bf2f(dd.y), bf2f(dd.z), bf2f(dd.w));
        {
            ushort4 bb = *(const ushort4*)&xdb[(size_t)(32 + g) * Lc + t0 + n * 4];
            ushort4 cc4 = *(const ushort4*)&xdb[(size_t)(48 + g) * Lc + t0 + n * 4];
            *(float4*)&sB[g][n * 4] = make_float4(bf2f(bb.x), bf2f(bb.y), bf2f(bb.z), bf2f(bb.w));
            *(float4*)&sC[g][n * 4] = make_float4(bf2f(cc4.x), bf2f(cc4.y), bf2f(cc4.z), bf2f(cc4.w));
        }
        __syncthreads();

#pragma unroll
        for (int s = 0; s < 4; s++) {
#pragma unroll
            for (int t2 = 0; t2 < 16; t2++) {
                int tt = s * 16 + t2;
                float dt = sDt[tt][g];
                float dA = __expf(dt * A_n);
                h = fmaf(dA, h, dt * sU[tt][g] * sB[n][tt]);
                sP[g][t2][n] = h * sC[n][tt];
            }
            // same-wave transposed reduce: lane (g,n) sums states for tt=s*16+n
            float4 p0 = *(float4*)&sP[g][n][0];
            float4 p1 = *(float4*)&sP[g][n][4];
            float4 p2 = *(float4*)&sP[g][n][8];
            float4 p3 = *(float4*)&sP[g][n][12];
            float acc = ((p0.x + p0.y) + (p0.z + p0.w)) + ((p1.x + p1.y) + (p1.z + p1.w)) +
                        ((p2.x + p2.y) + (p2.z + p2.w)) + ((p3.x + p3.y) + (p3.z + p3.w));
            int tt = s * 16 + n;
            int t  = t0 + tt;
            int gi = rev ? (Lc - 1 - t) : t;
            float val = (acc + Dv * sU[tt][g]) * siluf(bf2f(zp[gi]));
            sY[rev ? (63 - tt) : tt][g] = f2bf(val);
        }
        __syncthreads();

        // coalesced tile write
        {
            int trow = rev ? (Lc - 64 - t0 + srow) : (t0 + srow);
            size_t gidx = ((size_t)b * Lc + trow) * Ei + e0 + sc4;
            ushort4 tv = *(ushort4*)&sY[srow][sc4];
            if (rev) {
                ushort4 ov = *(ushort4*)&ybf[gidx];
                tv.x = f2bf(bf2f(tv.x) + bf2f(ov.x));
                tv.y = f2bf(bf2f(tv.y) + bf2f(ov.y));
                tv.z = f2bf(bf2f(tv.z) + bf2f(ov.z));
                tv.w = f2bf(bf2f(tv.w) + bf2f(ov.w));
            }
            *(ushort4*)&ybf[gidx] = tv;
        }
        __syncthreads();
    }
}

// ---------------------------------------------------------------------------
// K6: out_proj bf16 MFMA GEMM. out[b][n][m] = sum_e Wout[m][e]*ybf[b][n][e]
// ---------------------------------------------------------------------------
__global__ __launch_bounds__(256) void k_mfma_outproj(
    const unsigned short* __restrict__ Wbf,  // (512,1024) bf16
    const unsigned short* __restrict__ ybf,  // (4,2048,1024) bf16
    float* __restrict__ out)                 // (4,2048,512)
{
    const int b  = blockIdx.z;
    const int m0 = blockIdx.x * 64;
    const int n0 = blockIdx.y * 128;
    __shared__ __align__(16) unsigned short lA[64 * LDS_S];
    __shared__ __align__(16) unsigned short lB[128 * LDS_S];
    const int tid  = threadIdx.x;
    const int lane = tid & 63;
    const int w    = tid >> 6;
    const int wr   = w >> 1, wc = w & 1;

    f32x4 acc[2][4] = {};

    const unsigned short* yb = ybf + ((size_t)b * Lc + n0) * Ei;
    const unsigned short* Wb = Wbf + (size_t)m0 * Ei;

    for (int k0 = 0; k0 < Ei; k0 += 32) {
        {
            int c = tid;
            int row = c >> 2, col = (c & 3) * 8;
            *(uint4*)&lA[row * LDS_S + col] = *(const uint4*)&Wb[(size_t)row * Ei + k0 + col];
        }
#pragma unroll
        for (int i = 0; i < 2; i++) {
            int c = tid + i * 256;
            int row = c >> 2, col = (c & 3) * 8;
            *(uint4*)&lB[row * LDS_S + col] = *(const uint4*)&yb[(size_t)row * Ei + k0 + col];
        }
        __syncthreads();
        bf16x8 aF[2], bF[4];
#pragma unroll
        for (int f = 0; f < 2; f++)
            aF[f] = *(bf16x8*)&lA[(wr * 32 + f * 16 + (lane & 15)) * LDS_S + (lane >> 4) * 8];
#pragma unroll
        for (int f = 0; f < 4; f++)
            bF[f] = *(bf16x8*)&lB[(wc * 64 + f * 16 + (lane & 15)) * LDS_S + (lane >> 4) * 8];
#pragma unroll
        for (int i = 0; i < 2; i++)
#pragma unroll
            for (int j = 0; j < 4; j++)
                acc[i][j] = __builtin_amdgcn_mfma_f32_16x16x32_bf16(aF[i], bF[j], acc[i][j], 0, 0, 0);
        __syncthreads();
    }
    float* ob = out + (size_t)b * Lc * Dm;
#pragma unroll
    for (int i = 0; i < 2; i++) {
        int mm = m0 + wr * 32 + i * 16 + (lane >> 4) * 4;
#pragma unroll
        for (int j = 0; j < 4; j++) {
            int nn = n0 + wc * 64 + j * 16 + (lane & 15);
            *(f32x4*)&ob[(size_t)nn * Dm + mm] = acc[i][j];
        }
    }
}

// ---------------------------------------------------------------------------
// K7: fused residual add + RMSNorm (in place on d_out).
// ---------------------------------------------------------------------------
__global__ __launch_bounds__(256) void k_rms(float* __restrict__ out,
                                             const float* __restrict__ resid,
                                             const float* __restrict__ w) {
    int row  = blockIdx.x * 4 + (threadIdx.x >> 6);
    int lane = threadIdx.x & 63;
    float4* po = (float4*)(out + (size_t)row * Dm);
    const float4* pr = (const float4*)(resid + (size_t)row * Dm);
    const float4* pw = (const float4*)w;
    float4 a0 = po[lane], a1 = po[lane + 64];
    float4 r0 = pr[lane], r1 = pr[lane + 64];
    a0.x += r0.x; a0.y += r0.y; a0.z += r0.z; a0.w += r0.w;
    a1.x += r1.x; a1.y += r1.y; a1.z += r1.z; a1.w += r1.w;
    float q = a0.x * a0.x + a0.y * a0.y + a0.z * a0.z + a0.w * a0.w +
              a1.x * a1.x + a1.y * a1.y + a1.z * a1.z + a1.w * a1.w;
#pragma unroll
    for (int off = 32; off >= 1; off >>= 1) q += __shfl_xor(q, off);
    float scale = rsqrtf(q * (1.f / Dm) + EPSf);
    float4 w0 = pw[lane], w1 = pw[lane + 64];
    a0.x *= scale * w0.x; a0.y *= scale * w0.y; a0.z *= scale * w0.z; a0.w *= scale * w0.w;
    a1.x *= scale * w1.x; a1.y *= scale * w1.y; a1.z *= scale * w1.z; a1.w *= scale * w1.w;
    po[lane] = a0;
    po[lane + 64] = a1;
}

// ---------------------------------------------------------------------------
extern "C" void kernel_launch(void* const* d_in, const int* in_sizes, int n_in,
                              void* d_out, int out_size, void* d_ws, size_t ws_size,
                              hipStream_t stream) {
    const float* inp   = (const float*)d_in[0];
    const float* nw    = (const float*)d_in[1];
    const float* nbv   = (const float*)d_in[2];
    const float* Win   = (const float*)d_in[3];
    const float* cwf   = (const float*)d_in[4];
    const float* cbf   = (const float*)d_in[5];
    const float* xpwf  = (const float*)d_in[6];
    const float* dtwf  = (const float*)d_in[7];
    const float* dtbf  = (const float*)d_in[8];
    const float* Alogf = (const float*)d_in[9];
    const float* Df    = (const float*)d_in[10];
    const float* cwr   = (const float*)d_in[11];
    const float* cbr   = (const float*)d_in[12];
    const float* xpwr  = (const float*)d_in[13];
    const float* dtwr  = (const float*)d_in[14];
    const float* dtbr  = (const float*)d_in[15];
    const float* Alogr = (const float*)d_in[16];
    const float* Dr    = (const float*)d_in[17];
    const float* Wout  = (const float*)d_in[18];
    const float* nfw   = (const float*)d_in[19];
    float* outp = (float*)d_out;

    // workspace layout (ushort units)
    unsigned short* xz   = (unsigned short*)d_ws;            // 16,777,216
    unsigned short* xdbl = xz + (size_t)16777216;            //    524,288
    unsigned short* xcT  = xdbl + (size_t)524288;            //  8,388,608
    unsigned short* ybf  = xcT + (size_t)8388608;            //  8,388,608
    unsigned short* hbf  = ybf + (size_t)8388608;            //  4,194,304
    unsigned short* wbi  = hbf + (size_t)4194304;            //  1,048,576
    unsigned short* wbo  = wbi + (size_t)1048576;            //    524,288
    unsigned short* dt16 = wbo + (size_t)524288;             //  8,388,608
    unsigned short* xpbf = dt16 + (size_t)8388608;           //     65,536
    unsigned short* xpbr = xpbf + (size_t)65536;             //     65,536

    // P/S scratch lives in d_out (4.19M floats; overwritten by out_proj).
    float* Pb = outp;
    float* Sb = outp + 1048576;

    k_ln<<<2048, 256, 0, stream>>>(inp, nw, nbv, hbf);
    k_castall<<<1664, 256, 0, stream>>>(Win, wbi, Wout, wbo, xpwf, xpbf, xpwr, xpbr);
    k_mfma_inproj<<<dim3(16, 16, 4), 256, 0, stream>>>(wbi, hbf, xz);

    // forward branch
    k_conv<<<dim3(32, 64, 4), 256, 0, stream>>>(xz, cwf, cbf, xcT, 0);
    k_mfma_xdbl<<<dim3(16, 4), 256, 0, stream>>>(xpbf, xcT, xdbl);
    k_dt<<<dim3(32, 64, 4), 256, 0, stream>>>(xdbl, dtwf, dtbf, dt16);
    k_scan_p1<<<NCH * 256, 256, 0, stream>>>(xcT, xdbl, dt16, Alogf, Pb, Sb);
    k_scan_p2<<<NCH * 256, 256, 0, stream>>>(xcT, xdbl, xz, dt16, Alogf, Df, Pb, Sb, ybf, 0);

    // reverse branch (index-reversed, accumulates into ybf)
    k_conv<<<dim3(32, 64, 4), 256, 0, stream>>>(xz, cwr, cbr, xcT, 1);
    k_mfma_xdbl<<<dim3(16, 4), 256, 0, stream>>>(xpbr, xcT, xdbl);
    k_dt<<<dim3(32, 64, 4), 256, 0, stream>>>(xdbl, dtwr, dtbr, dt16);
    k_scan_p1<<<NCH * 256, 256, 0, stream>>>(xcT, xdbl, dt16, Alogr, Pb, Sb);
    k_scan_p2<<<NCH * 256, 256, 0, stream>>>(xcT, xdbl, xz, dt16, Alogr, Dr, Pb, Sb, ybf, 1);

    k_mfma_outproj<<<dim3(8, 16, 4), 256, 0, stream>>>(wbo, ybf, outp);
    k_rms<<<2048, 256, 0, stream>>>(outp, inp, nfw);
}

// Round 9
// 439.289 us; speedup vs baseline: 1.4197x; 1.0003x over previous
//
#include <hip/hip_runtime.h>
#include <math.h>
#include <stdint.h>

// Problem constants
#define Bb 4
#define Lc 2048
#define Dm 512
#define Ei 1024     // E = 2*D_MODEL
#define Ns 16       // d_state
#define Rr 32       // dt_rank
#define EPSf 1e-5f
#define NCH 16      // scan chunks
#define TCH 128     // timesteps per chunk
#define LDS_S 40    // padded LDS row stride (ushorts) for MFMA tiles
#define NXCD 8

typedef __attribute__((ext_vector_type(8))) short bf16x8;
typedef __attribute__((ext_vector_type(4))) float f32x4;

__device__ __forceinline__ float siluf(float x) {
    return x / (1.f + __expf(-x));
}
__device__ __forceinline__ float softplusf(float x) {
    return x > 20.f ? x : log1pf(__expf(x));
}
__device__ __forceinline__ unsigned short f2bf(float x) {
    union { float f; unsigned u; } v; v.f = x;
    unsigned r = (v.u + 0x7FFFu + ((v.u >> 16) & 1u)) >> 16;
    return (unsigned short)r;
}
__device__ __forceinline__ float bf2f(unsigned short x) {
    union { unsigned u; float f; } v; v.u = ((unsigned)x) << 16;
    return v.f;
}

// ---------------------------------------------------------------------------
// K1: LayerNorm -> bf16 h. One wave per row (D=512), 4 rows/block.
// ---------------------------------------------------------------------------
__global__ __launch_bounds__(256) void k_ln(const float* __restrict__ inp,
                                            const float* __restrict__ nw,
                                            const float* __restrict__ nb,
                                            unsigned short* __restrict__ hbf) {
    int row  = blockIdx.x * 4 + (threadIdx.x >> 6);
    int lane = threadIdx.x & 63;
    const float4* p = (const float4*)(inp + (size_t)row * Dm);
    float4 v0 = p[lane];
    float4 v1 = p[lane + 64];
    float s = v0.x + v0.y + v0.z + v0.w + v1.x + v1.y + v1.z + v1.w;
    float q = v0.x * v0.x + v0.y * v0.y + v0.z * v0.z + v0.w * v0.w +
              v1.x * v1.x + v1.y * v1.y + v1.z * v1.z + v1.w * v1.w;
#pragma unroll
    for (int off = 32; off >= 1; off >>= 1) {
        s += __shfl_xor(s, off);
        q += __shfl_xor(q, off);
    }
    float mu = s * (1.f / Dm);
    float rs = rsqrtf(q * (1.f / Dm) - mu * mu + EPSf);
    int d0 = lane * 4, d1 = 256 + lane * 4;
    float4 w0 = *(const float4*)&nw[d0], w1 = *(const float4*)&nw[d1];
    float4 b0 = *(const float4*)&nb[d0], b1 = *(const float4*)&nb[d1];
    ushort4 o0, o1;
    o0.x = f2bf((v0.x - mu) * rs * w0.x + b0.x);
    o0.y = f2bf((v0.y - mu) * rs * w0.y + b0.y);
    o0.z = f2bf((v0.z - mu) * rs * w0.z + b0.z);
    o0.w = f2bf((v0.w - mu) * rs * w0.w + b0.w);
    o1.x = f2bf((v1.x - mu) * rs * w1.x + b1.x);
    o1.y = f2bf((v1.y - mu) * rs * w1.y + b1.y);
    o1.z = f2bf((v1.z - mu) * rs * w1.z + b1.z);
    o1.w = f2bf((v1.w - mu) * rs * w1.w + b1.w);
    *(ushort4*)&hbf[(size_t)row * Dm + d0] = o0;
    *(ushort4*)&hbf[(size_t)row * Dm + d1] = o1;
}

// ---------------------------------------------------------------------------
// K1b: merged fp32 -> bf16 cast of all four weight tensors. Quad-indexed.
// ---------------------------------------------------------------------------
__global__ __launch_bounds__(256) void k_castall(
    const float* __restrict__ Win,  unsigned short* __restrict__ wbi,
    const float* __restrict__ Wout, unsigned short* __restrict__ wbo,
    const float* __restrict__ xpf,  unsigned short* __restrict__ xpbf,
    const float* __restrict__ xpr,  unsigned short* __restrict__ xpbr) {
    size_t q = (size_t)blockIdx.x * 256 + threadIdx.x;  // quad index
    const float* src; unsigned short* dst; size_t off;
    if (q < 262144)      { src = Win;  dst = wbi;  off = q; }
    else if (q < 393216) { src = Wout; dst = wbo;  off = q - 262144; }
    else if (q < 409600) { src = xpf;  dst = xpbf; off = q - 393216; }
    else                 { src = xpr;  dst = xpbr; off = q - 409600; }
    float4 v = ((const float4*)src)[off];
    ushort4 o;
    o.x = f2bf(v.x); o.y = f2bf(v.y); o.z = f2bf(v.z); o.w = f2bf(v.w);
    ((ushort4*)dst)[off] = o;
}

// ---------------------------------------------------------------------------
// K2: in_proj bf16 MFMA GEMM.  xz[b][m][n] = sum_k W[m][k] * h[b*L+n][k]
// ---------------------------------------------------------------------------
__global__ __launch_bounds__(256) void k_mfma_inproj(
    const unsigned short* __restrict__ Wbf,  // (2048,512) bf16
    const unsigned short* __restrict__ hbf,  // (8192,512) bf16
    unsigned short* __restrict__ xz)         // (4,2048,2048) bf16
{
    const int b  = blockIdx.z;
    const int m0 = blockIdx.x * 128;
    const int n0 = blockIdx.y * 128;
    __shared__ __align__(16) unsigned short lA[128 * LDS_S];
    __shared__ __align__(16) unsigned short lB[128 * LDS_S];
    const int tid  = threadIdx.x;
    const int lane = tid & 63;
    const int w    = tid >> 6;
    const int wr   = w >> 1, wc = w & 1;

    f32x4 acc[4][4] = {};

    const unsigned short* hb = hbf + ((size_t)b * Lc + n0) * Dm;
    const unsigned short* Wb = Wbf + (size_t)m0 * Dm;

    for (int k0 = 0; k0 < Dm; k0 += 32) {
#pragma unroll
        for (int i = 0; i < 2; i++) {
            int c = tid + i * 256;            // 512 16B-chunks per tile
            int row = c >> 2, col = (c & 3) * 8;
            *(uint4*)&lA[row * LDS_S + col] = *(const uint4*)&Wb[(size_t)row * Dm + k0 + col];
            *(uint4*)&lB[row * LDS_S + col] = *(const uint4*)&hb[(size_t)row * Dm + k0 + col];
        }
        __syncthreads();
        bf16x8 aF[4], bF[4];
#pragma unroll
        for (int f = 0; f < 4; f++) {
            aF[f] = *(bf16x8*)&lA[(wr * 64 + f * 16 + (lane & 15)) * LDS_S + (lane >> 4) * 8];
            bF[f] = *(bf16x8*)&lB[(wc * 64 + f * 16 + (lane & 15)) * LDS_S + (lane >> 4) * 8];
        }
#pragma unroll
        for (int i = 0; i < 4; i++)
#pragma unroll
            for (int j = 0; j < 4; j++)
                acc[i][j] = __builtin_amdgcn_mfma_f32_16x16x32_bf16(aF[i], bF[j], acc[i][j], 0, 0, 0);
        __syncthreads();
    }
    unsigned short* Cb = xz + (size_t)b * 2048 * Lc;
#pragma unroll
    for (int i = 0; i < 4; i++) {
        int mbase = m0 + wr * 64 + i * 16 + (lane >> 4) * 4;
#pragma unroll
        for (int j = 0; j < 4; j++) {
            int nn = n0 + wc * 64 + j * 16 + (lane & 15);
#pragma unroll
            for (int r = 0; r < 4; r++)
                Cb[(size_t)(mbase + r) * Lc + nn] = f2bf(acc[i][j][r]);
        }
    }
}

// ---------------------------------------------------------------------------
// K3: tiled causal depthwise conv (K=4) + SiLU on bf16 xz.
// Emits xcT [b][L][e] bf16 via LDS transpose tile.
// ---------------------------------------------------------------------------
__global__ __launch_bounds__(256) void k_conv(const unsigned short* __restrict__ xz,
                                              const float* __restrict__ cw,
                                              const float* __restrict__ cb,
                                              unsigned short* __restrict__ xcT,
                                              int rev) {
    const int b  = blockIdx.z;
    const int e0 = blockIdx.y * 16;
    const int t0 = blockIdx.x * 64;
    const int tid = threadIdx.x;
    const int g = tid >> 4;
    const int n = tid & 15;
    const int e = e0 + g;
    const int j0 = t0 + n * 4;

    __shared__ unsigned short sY[64][20];   // stride 40 B: ushort4-aligned rows

    const unsigned short* x = xz + ((size_t)b * 2048 + e) * Lc;
    float w0 = cw[e * 4], w1 = cw[e * 4 + 1], w2 = cw[e * 4 + 2], w3 = cw[e * 4 + 3];
    float bias = cb[e];

    float v[8];  // xin[j0-4 .. j0+3] (xin = x or reversed x)
    if (!rev) {
        ushort4 cur = *(const ushort4*)&x[j0];
        v[4] = bf2f(cur.x); v[5] = bf2f(cur.y); v[6] = bf2f(cur.z); v[7] = bf2f(cur.w);
        if (j0 >= 4) {
            ushort4 prv = *(const ushort4*)&x[j0 - 4];
            v[0] = bf2f(prv.x); v[1] = bf2f(prv.y); v[2] = bf2f(prv.z); v[3] = bf2f(prv.w);
        } else { v[0] = v[1] = v[2] = v[3] = 0.f; }
    } else {
        ushort4 c4 = *(const ushort4*)&x[Lc - 4 - j0];
        v[4] = bf2f(c4.w); v[5] = bf2f(c4.z); v[6] = bf2f(c4.y); v[7] = bf2f(c4.x);
        if (j0 >= 4) {
            ushort4 p4 = *(const ushort4*)&x[Lc - j0];
            v[0] = bf2f(p4.w); v[1] = bf2f(p4.z); v[2] = bf2f(p4.y); v[3] = bf2f(p4.x);
        } else { v[0] = v[1] = v[2] = v[3] = 0.f; }
    }

#pragma unroll
    for (int jj = 0; jj < 4; jj++) {
        float a = bias + w0 * v[jj + 1] + w1 * v[jj + 2] + w2 * v[jj + 3] + w3 * v[jj + 4];
        sY[n * 4 + jj][g] = f2bf(siluf(a));
    }
    __syncthreads();

    int row = tid >> 2;
    int c4  = (tid & 3) * 4;
    ushort4 tv = *(ushort4*)&sY[row][c4];
    *(ushort4*)&xcT[((size_t)b * Lc + t0 + row) * Ei + e0 + c4] = tv;
}

// ---------------------------------------------------------------------------
// K4: x_proj bf16 MFMA GEMM: xdbl[b][m][n] = sum_e xpw[m][e] * xcT[b][n][e]
// Output bf16.
// ---------------------------------------------------------------------------
__global__ __launch_bounds__(256) void k_mfma_xdbl(
    const unsigned short* __restrict__ xpb,  // (64,1024) bf16
    const unsigned short* __restrict__ xcT,  // (4,2048,1024) bf16
    unsigned short* __restrict__ xdbl)       // (4,64,2048) bf16
{
    const int n0 = blockIdx.x * 128;
    const int b  = blockIdx.y;
    __shared__ __align__(16) unsigned short lA[64 * LDS_S];
    __shared__ __align__(16) unsigned short lB[128 * LDS_S];
    const int tid  = threadIdx.x;
    const int lane = tid & 63;
    const int w    = tid >> 6;

    f32x4 acc[4][2] = {};

    const unsigned short* yb = xcT + ((size_t)b * Lc + n0) * Ei;

    for (int k0 = 0; k0 < Ei; k0 += 32) {
        {
            int c = tid;
            int row = c >> 2, col = (c & 3) * 8;
            *(uint4*)&lA[row * LDS_S + col] = *(const uint4*)&xpb[(size_t)row * Ei + k0 + col];
        }
#pragma unroll
        for (int i = 0; i < 2; i++) {
            int c = tid + i * 256;
            int row = c >> 2, col = (c & 3) * 8;
            *(uint4*)&lB[row * LDS_S + col] = *(const uint4*)&yb[(size_t)row * Ei + k0 + col];
        }
        __syncthreads();
        bf16x8 aF[4], bF[2];
#pragma unroll
        for (int f = 0; f < 4; f++)
            aF[f] = *(bf16x8*)&lA[(f * 16 + (lane & 15)) * LDS_S + (lane >> 4) * 8];
#pragma unroll
        for (int f = 0; f < 2; f++)
            bF[f] = *(bf16x8*)&lB[(w * 32 + f * 16 + (lane & 15)) * LDS_S + (lane >> 4) * 8];
#pragma unroll
        for (int i = 0; i < 4; i++)
#pragma unroll
            for (int j = 0; j < 2; j++)
                acc[i][j] = __builtin_amdgcn_mfma_f32_16x16x32_bf16(aF[i], bF[j], acc[i][j], 0, 0, 0);
        __syncthreads();
    }
    unsigned short* xd = xdbl + (size_t)b * 64 * Lc;
#pragma unroll
    for (int i = 0; i < 4; i++) {
        int mbase = i * 16 + (lane >> 4) * 4;
#pragma unroll
        for (int j = 0; j < 2; j++) {
            int nn = n0 + w * 32 + j * 16 + (lane & 15);
#pragma unroll
            for (int r = 0; r < 4; r++)
                xd[(size_t)(mbase + r) * Lc + nn] = f2bf(acc[i][j][r]);
        }
    }
}

// ---------------------------------------------------------------------------
// K4b: dt = softplus(dtw @ dt_low + bias).  Output bf16 [b][t][e] via LDS
// transpose tile.  Block: 16 e x 64 t.
// ---------------------------------------------------------------------------
__global__ __launch_bounds__(256) void k_dt(
    const unsigned short* __restrict__ xdbl, // (4,64,2048) bf16; rows 0..31 dt_low
    const float* __restrict__ dtw,   // (1024,32)
    const float* __restrict__ dtb,   // (1024)
    unsigned short* __restrict__ dt16) // (4,2048,1024) bf16 [t][e]
{
    const int b  = blockIdx.z;
    const int e0 = blockIdx.y * 16;
    const int t0 = blockIdx.x * 64;
    const int tid = threadIdx.x;
    const int g = tid >> 4;          // local e
    const int n = tid & 15;          // t-quad selector
    const int e = e0 + g;

    __shared__ float sW[16][33];
    __shared__ float sDtl[32][68];
    __shared__ unsigned short sT[64][20];

    for (int i = tid; i < 512; i += 256)
        sW[i >> 5][i & 31] = dtw[(size_t)(e0 + (i >> 5)) * 32 + (i & 31)];

    const unsigned short* xdb = xdbl + (size_t)b * 64 * Lc;
#pragma unroll
    for (int f = 0; f < 2; f++) {
        int fi = tid * 2 + f;            // 512 quad slots (32 rows x 16 quads)
        int row = fi >> 4, c4 = (fi & 15) * 4;
        ushort4 q = *(const ushort4*)&xdb[(size_t)row * Lc + t0 + c4];
        *(float4*)&sDtl[row][c4] = make_float4(bf2f(q.x), bf2f(q.y), bf2f(q.z), bf2f(q.w));
    }
    __syncthreads();

    const float bias = dtb[e];
#pragma unroll
    for (int jj = 0; jj < 4; jj++) {
        int tt = n * 4 + jj;
        float a = bias;
#pragma unroll
        for (int r = 0; r < 32; r++) a += sDtl[r][tt] * sW[g][r];
        sT[tt][g] = f2bf(softplusf(a));
    }
    __syncthreads();

    int row = tid >> 2;
    int c4  = (tid & 3) * 4;
    ushort4 tv = *(ushort4*)&sT[row][c4];
    *(ushort4*)&dt16[((size_t)b * Lc + t0 + row) * Ei + e0 + c4] = tv;
}

// ---------------------------------------------------------------------------
// K5a: scan pass 1 — per-chunk affine transform (P = prod dA, S = local h).
// XCD-swizzled blockIdx (adjacent e0-blocks share an XCD's L2, absorbing the
// 32B-of-cache-line tile reads). sDu precomputed at stage time.
// ---------------------------------------------------------------------------
__global__ __launch_bounds__(256) void k_scan_p1(
    const unsigned short* __restrict__ xcT,   // u bf16 [b][t][e]
    const unsigned short* __restrict__ xdbl,  // bf16 (4,64,2048)
    const unsigned short* __restrict__ dt16,  // bf16 [b][t][e]
    const float* __restrict__ Alog,
    float* __restrict__ Pbuf,          // [NCH][4][1024][16]
    float* __restrict__ Sbuf)
{
    const int nb  = NCH * 256;
    const int raw = blockIdx.x;
    const int bx  = (raw % NXCD) * (nb / NXCD) + raw / NXCD;   // XCD swizzle
    const int c  = bx >> 8;
    const int j  = bx & 255;
    const int b  = j >> 6;
    const int e0 = (j & 63) << 4;
    const int tid = threadIdx.x;
    const int g = tid >> 4;
    const int n = tid & 15;
    const int e = e0 + g;
    const int srow = tid >> 2;
    const int sc4  = (tid & 3) * 4;

    __shared__ float sDt[64][20];
    __shared__ float sDu[64][20];
    __shared__ float sB[16][68];

    const float A_n = -__expf(Alog[(size_t)e * Ns + n]);
    float h = 0.f, Pa = 1.f;

    const unsigned short* uT = xcT + (size_t)b * Lc * Ei;
    const unsigned short* dT = dt16 + (size_t)b * Lc * Ei;
    const unsigned short* xdb = xdbl + (size_t)b * 64 * Lc;

    const int tbeg = c * TCH;
    for (int t0 = tbeg; t0 < tbeg + TCH; t0 += 64) {
        ushort4 uu = *(const ushort4*)&uT[(size_t)(t0 + srow) * Ei + e0 + sc4];
        ushort4 dd = *(const ushort4*)&dT[(size_t)(t0 + srow) * Ei + e0 + sc4];
        float4 dtq = make_float4(bf2f(dd.x), bf2f(dd.y), bf2f(dd.z), bf2f(dd.w));
        *(float4*)&sDt[srow][sc4] = dtq;
        *(float4*)&sDu[srow][sc4] = make_float4(dtq.x * bf2f(uu.x), dtq.y * bf2f(uu.y),
                                                dtq.z * bf2f(uu.z), dtq.w * bf2f(uu.w));
        {   // B row stage: lane (g,n) reads row 32+g, cols t0+n*4 (coalesced)
            ushort4 bb = *(const ushort4*)&xdb[(size_t)(32 + g) * Lc + t0 + n * 4];
            *(float4*)&sB[g][n * 4] = make_float4(bf2f(bb.x), bf2f(bb.y), bf2f(bb.z), bf2f(bb.w));
        }
        __syncthreads();
#pragma unroll
        for (int tt = 0; tt < 64; tt++) {
            float dA = __expf(sDt[tt][g] * A_n);
            h  = fmaf(dA, h, sDu[tt][g] * sB[n][tt]);
            Pa *= dA;
        }
        __syncthreads();
    }
    size_t idx = ((size_t)(c * 4 + b) * 1024 + e) * 16 + n;
    Pbuf[idx] = Pa;
    Sbuf[idx] = h;
}

// ---------------------------------------------------------------------------
// K5c: scan pass 2 — XCD-swizzled; per-block h_in composition; sDu
// precomputed; y via sP-transpose reduce; gated bf16 output via sY tile.
// ---------------------------------------------------------------------------
__global__ __launch_bounds__(256) void k_scan_p2(
    const unsigned short* __restrict__ xcT,   // u bf16 [b][t][e]
    const unsigned short* __restrict__ xdbl,  // bf16 (4,64,2048)
    const unsigned short* __restrict__ xz,    // bf16; z rows Ei..2Ei-1
    const unsigned short* __restrict__ dt16,  // bf16 [b][t][e]
    const float* __restrict__ Alog,
    const float* __restrict__ Dp,
    const float* __restrict__ Pbuf,    // [NCH][4][1024][16]
    const float* __restrict__ Sbuf,
    unsigned short* __restrict__ ybf,  // (4,2048,1024) bf16
    int rev)
{
    const int nb  = NCH * 256;
    const int raw = blockIdx.x;
    const int bx  = (raw % NXCD) * (nb / NXCD) + raw / NXCD;   // XCD swizzle
    const int c  = bx >> 8;
    const int j  = bx & 255;
    const int b  = j >> 6;
    const int e0 = (j & 63) << 4;
    const int tid = threadIdx.x;
    const int g = tid >> 4;
    const int n = tid & 15;
    const int e = e0 + g;
    const int srow = tid >> 2;
    const int sc4  = (tid & 3) * 4;

    __shared__ float sDt[64][20];
    __shared__ float sDu[64][20];
    __shared__ float sU[64][20];
    __shared__ float sB[16][68];
    __shared__ float sC[16][68];
    __shared__ float sP[16][17][20];
    __shared__ unsigned short sY[64][20];

    const float A_n = -__expf(Alog[(size_t)e * Ns + n]);
    const float Dv  = Dp[e];

    // folded mid kernel: compose h_in from chunks 0..c-1
    float h = 0.f;
    for (int cc = 0; cc < c; cc++) {
        size_t pidx = ((size_t)(cc * 4 + b) * 1024 + e) * 16 + n;
        h = Sbuf[pidx] + Pbuf[pidx] * h;
    }

    const unsigned short* uT = xcT + (size_t)b * Lc * Ei;
    const unsigned short* dT = dt16 + (size_t)b * Lc * Ei;
    const unsigned short* zp = xz + ((size_t)b * 2048 + Ei + e) * Lc;
    const unsigned short* xdb = xdbl + (size_t)b * 64 * Lc;

    const int tbeg = c * TCH;
    for (int t0 = tbeg; t0 < tbeg + TCH; t0 += 64) {
        ushort4 uu = *(const ushort4*)&uT[(size_t)(t0 + srow) * Ei + e0 + sc4];
        ushort4 dd = *(const ushort4*)&dT[(size_t)(t0 + srow) * Ei + e0 + sc4];
        float4 uq  = make_float4(bf2f(uu.x), bf2f(uu.y), bf2f(uu.z), bf2f(uu.w));
        float4 dtq = make_float4(bf2f(dd.x), bf2f(dd.y), bf2f(dd.z), bf2f(dd.w));
        *(float4*)&sU[srow][sc4]  = uq;
        *(float4*)&sDt[srow][sc4] = dtq;
        *(float4*)&sDu[srow][sc4] = make_float4(dtq.x * uq.x, dtq.y * uq.y,
                                                dtq.z * uq.z, dtq.w * uq.w);
        {
            ushort4 bb  = *(const ushort4*)&xdb[(size_t)(32 + g) * Lc + t0 + n * 4];
            ushort4 cc4 = *(const ushort4*)&xdb[(size_t)(48 + g) * Lc + t0 + n * 4];
            *(float4*)&sB[g][n * 4] = make_float4(bf2f(bb.x), bf2f(bb.y), bf2f(bb.z), bf2f(bb.w));
            *(float4*)&sC[g][n * 4] = make_float4(bf2f(cc4.x), bf2f(cc4.y), bf2f(cc4.z), bf2f(cc4.w));
        }
        __syncthreads();

#pragma unroll
        for (int s = 0; s < 4; s++) {
#pragma unroll
            for (int t2 = 0; t2 < 16; t2++) {
                int tt = s * 16 + t2;
                float dA = __expf(sDt[tt][g] * A_n);
                h = fmaf(dA, h, sDu[tt][g] * sB[n][tt]);
                sP[g][t2][n] = h * sC[n][tt];
            }
            // same-wave transposed reduce: lane (g,n) sums states for tt=s*16+n
            float4 p0 = *(float4*)&sP[g][n][0];
            float4 p1 = *(float4*)&sP[g][n][4];
            float4 p2 = *(float4*)&sP[g][n][8];
            float4 p3 = *(float4*)&sP[g][n][12];
            float acc = ((p0.x + p0.y) + (p0.z + p0.w)) + ((p1.x + p1.y) + (p1.z + p1.w)) +
                        ((p2.x + p2.y) + (p2.z + p2.w)) + ((p3.x + p3.y) + (p3.z + p3.w));
            int tt = s * 16 + n;
            int t  = t0 + tt;
            int gi = rev ? (Lc - 1 - t) : t;
            float val = (acc + Dv * sU[tt][g]) * siluf(bf2f(zp[gi]));
            sY[rev ? (63 - tt) : tt][g] = f2bf(val);
        }
        __syncthreads();

        // coalesced tile write
        {
            int trow = rev ? (Lc - 64 - t0 + srow) : (t0 + srow);
            size_t gidx = ((size_t)b * Lc + trow) * Ei + e0 + sc4;
            ushort4 tv = *(ushort4*)&sY[srow][sc4];
            if (rev) {
                ushort4 ov = *(ushort4*)&ybf[gidx];
                tv.x = f2bf(bf2f(tv.x) + bf2f(ov.x));
                tv.y = f2bf(bf2f(tv.y) + bf2f(ov.y));
                tv.z = f2bf(bf2f(tv.z) + bf2f(ov.z));
                tv.w = f2bf(bf2f(tv.w) + bf2f(ov.w));
            }
            *(ushort4*)&ybf[gidx] = tv;
        }
        __syncthreads();
    }
}

// ---------------------------------------------------------------------------
// K6: out_proj bf16 MFMA GEMM. out[b][n][m] = sum_e Wout[m][e]*ybf[b][n][e]
// ---------------------------------------------------------------------------
__global__ __launch_bounds__(256) void k_mfma_outproj(
    const unsigned short* __restrict__ Wbf,  // (512,1024) bf16
    const unsigned short* __restrict__ ybf,  // (4,2048,1024) bf16
    float* __restrict__ out)                 // (4,2048,512)
{
    const int b  = blockIdx.z;
    const int m0 = blockIdx.x * 64;
    const int n0 = blockIdx.y * 128;
    __shared__ __align__(16) unsigned short lA[64 * LDS_S];
    __shared__ __align__(16) unsigned short lB[128 * LDS_S];
    const int tid  = threadIdx.x;
    const int lane = tid & 63;
    const int w    = tid >> 6;
    const int wr   = w >> 1, wc = w & 1;

    f32x4 acc[2][4] = {};

    const unsigned short* yb = ybf + ((size_t)b * Lc + n0) * Ei;
    const unsigned short* Wb = Wbf + (size_t)m0 * Ei;

    for (int k0 = 0; k0 < Ei; k0 += 32) {
        {
            int c = tid;
            int row = c >> 2, col = (c & 3) * 8;
            *(uint4*)&lA[row * LDS_S + col] = *(const uint4*)&Wb[(size_t)row * Ei + k0 + col];
        }
#pragma unroll
        for (int i = 0; i < 2; i++) {
            int c = tid + i * 256;
            int row = c >> 2, col = (c & 3) * 8;
            *(uint4*)&lB[row * LDS_S + col] = *(const uint4*)&yb[(size_t)row * Ei + k0 + col];
        }
        __syncthreads();
        bf16x8 aF[2], bF[4];
#pragma unroll
        for (int f = 0; f < 2; f++)
            aF[f] = *(bf16x8*)&lA[(wr * 32 + f * 16 + (lane & 15)) * LDS_S + (lane >> 4) * 8];
#pragma unroll
        for (int f = 0; f < 4; f++)
            bF[f] = *(bf16x8*)&lB[(wc * 64 + f * 16 + (lane & 15)) * LDS_S + (lane >> 4) * 8];
#pragma unroll
        for (int i = 0; i < 2; i++)
#pragma unroll
            for (int j = 0; j < 4; j++)
                acc[i][j] = __builtin_amdgcn_mfma_f32_16x16x32_bf16(aF[i], bF[j], acc[i][j], 0, 0, 0);
        __syncthreads();
    }
    float* ob = out + (size_t)b * Lc * Dm;
#pragma unroll
    for (int i = 0; i < 2; i++) {
        int mm = m0 + wr * 32 + i * 16 + (lane >> 4) * 4;
#pragma unroll
        for (int j = 0; j < 4; j++) {
            int nn = n0 + wc * 64 + j * 16 + (lane & 15);
            *(f32x4*)&ob[(size_t)nn * Dm + mm] = acc[i][j];
        }
    }
}

// ---------------------------------------------------------------------------
// K7: fused residual add + RMSNorm (in place on d_out).
// ---------------------------------------------------------------------------
__global__ __launch_bounds__(256) void k_rms(float* __restrict__ out,
                                             const float* __restrict__ resid,
                                             const float* __restrict__ w) {
    int row  = blockIdx.x * 4 + (threadIdx.x >> 6);
    int lane = threadIdx.x & 63;
    float4* po = (float4*)(out + (size_t)row * Dm);
    const float4* pr = (const float4*)(resid + (size_t)row * Dm);
    const float4* pw = (const float4*)w;
    float4 a0 = po[lane], a1 = po[lane + 64];
    float4 r0 = pr[lane], r1 = pr[lane + 64];
    a0.x += r0.x; a0.y += r0.y; a0.z += r0.z; a0.w += r0.w;
    a1.x += r1.x; a1.y += r1.y; a1.z += r1.z; a1.w += r1.w;
    float q = a0.x * a0.x + a0.y * a0.y + a0.z * a0.z + a0.w * a0.w +
              a1.x * a1.x + a1.y * a1.y + a1.z * a1.z + a1.w * a1.w;
#pragma unroll
    for (int off = 32; off >= 1; off >>= 1) q += __shfl_xor(q, off);
    float scale = rsqrtf(q * (1.f / Dm) + EPSf);
    float4 w0 = pw[lane], w1 = pw[lane + 64];
    a0.x *= scale * w0.x; a0.y *= scale * w0.y; a0.z *= scale * w0.z; a0.w *= scale * w0.w;
    a1.x *= scale * w1.x; a1.y *= scale * w1.y; a1.z *= scale * w1.z; a1.w *= scale * w1.w;
    po[lane] = a0;
    po[lane + 64] = a1;
}

// ---------------------------------------------------------------------------
extern "C" void kernel_launch(void* const* d_in, const int* in_sizes, int n_in,
                              void* d_out, int out_size, void* d_ws, size_t ws_size,
                              hipStream_t stream) {
    const float* inp   = (const float*)d_in[0];
    const float* nw    = (const float*)d_in[1];
    const float* nbv   = (const float*)d_in[2];
    const float* Win   = (const float*)d_in[3];
    const float* cwf   = (const float*)d_in[4];
    const float* cbf   = (const float*)d_in[5];
    const float* xpwf  = (const float*)d_in[6];
    const float* dtwf  = (const float*)d_in[7];
    const float* dtbf  = (const float*)d_in[8];
    const float* Alogf = (const float*)d_in[9];
    const float* Df    = (const float*)d_in[10];
    const float* cwr   = (const float*)d_in[11];
    const float* cbr   = (const float*)d_in[12];
    const float* xpwr  = (const float*)d_in[13];
    const float* dtwr  = (const float*)d_in[14];
    const float* dtbr  = (const float*)d_in[15];
    const float* Alogr = (const float*)d_in[16];
    const float* Dr    = (const float*)d_in[17];
    const float* Wout  = (const float*)d_in[18];
    const float* nfw   = (const float*)d_in[19];
    float* outp = (float*)d_out;

    // workspace layout (ushort units)
    unsigned short* xz   = (unsigned short*)d_ws;            // 16,777,216
    unsigned short* xdbl = xz + (size_t)16777216;            //    524,288
    unsigned short* xcT  = xdbl + (size_t)524288;            //  8,388,608
    unsigned short* ybf  = xcT + (size_t)8388608;            //  8,388,608
    unsigned short* hbf  = ybf + (size_t)8388608;            //  4,194,304
    unsigned short* wbi  = hbf + (size_t)4194304;            //  1,048,576
    unsigned short* wbo  = wbi + (size_t)1048576;            //    524,288
    unsigned short* dt16 = wbo + (size_t)524288;             //  8,388,608
    unsigned short* xpbf = dt16 + (size_t)8388608;           //     65,536
    unsigned short* xpbr = xpbf + (size_t)65536;             //     65,536

    // P/S scratch lives in d_out (4.19M floats; overwritten by out_proj).
    float* Pb = outp;
    float* Sb = outp + 1048576;

    k_ln<<<2048, 256, 0, stream>>>(inp, nw, nbv, hbf);
    k_castall<<<1664, 256, 0, stream>>>(Win, wbi, Wout, wbo, xpwf, xpbf, xpwr, xpbr);
    k_mfma_inproj<<<dim3(16, 16, 4), 256, 0, stream>>>(wbi, hbf, xz);

    // forward branch
    k_conv<<<dim3(32, 64, 4), 256, 0, stream>>>(xz, cwf, cbf, xcT, 0);
    k_mfma_xdbl<<<dim3(16, 4), 256, 0, stream>>>(xpbf, xcT, xdbl);
    k_dt<<<dim3(32, 64, 4), 256, 0, stream>>>(xdbl, dtwf, dtbf, dt16);
    k_scan_p1<<<NCH * 256, 256, 0, stream>>>(xcT, xdbl, dt16, Alogf, Pb, Sb);
    k_scan_p2<<<NCH * 256, 256, 0, stream>>>(xcT, xdbl, xz, dt16, Alogf, Df, Pb, Sb, ybf, 0);

    // reverse branch (index-reversed, accumulates into ybf)
    k_conv<<<dim3(32, 64, 4), 256, 0, stream>>>(xz, cwr, cbr, xcT, 1);
    k_mfma_xdbl<<<dim3(16, 4), 256, 0, stream>>>(xpbr, xcT, xdbl);
    k_dt<<<dim3(32, 64, 4), 256, 0, stream>>>(xdbl, dtwr, dtbr, dt16);
    k_scan_p1<<<NCH * 256, 256, 0, stream>>>(xcT, xdbl, dt16, Alogr, Pb, Sb);
    k_scan_p2<<<NCH * 256, 256, 0, stream>>>(xcT, xdbl, xz, dt16, Alogr, Dr, Pb, Sb, ybf, 1);

    k_mfma_outproj<<<dim3(8, 16, 4), 256, 0, stream>>>(wbo, ybf, outp);
    k_rms<<<2048, 256, 0, stream>>>(outp, inp, nfw);
}

// Round 10
// 403.132 us; speedup vs baseline: 1.5471x; 1.0897x over previous
//
#include <hip/hip_runtime.h>
#include <math.h>
#include <stdint.h>

// Problem constants
#define Bb 4
#define Lc 2048
#define Dm 512
#define Ei 1024     // E = 2*D_MODEL
#define Ns 16       // d_state
#define Rr 32       // dt_rank
#define EPSf 1e-5f
#define NCH 16      // scan chunks
#define TCH 128     // timesteps per chunk
#define LDS_S 40    // padded LDS row stride (ushorts) for MFMA tiles
#define NXCD 8

typedef __attribute__((ext_vector_type(8))) short bf16x8;
typedef __attribute__((ext_vector_type(4))) float f32x4;

__device__ __forceinline__ float siluf(float x) {
    return x / (1.f + __expf(-x));
}
__device__ __forceinline__ float softplusf(float x) {
    return x > 20.f ? x : log1pf(__expf(x));
}
__device__ __forceinline__ unsigned short f2bf(float x) {
    union { float f; unsigned u; } v; v.f = x;
    unsigned r = (v.u + 0x7FFFu + ((v.u >> 16) & 1u)) >> 16;
    return (unsigned short)r;
}
__device__ __forceinline__ unsigned short f2bf_trunc(float x) {
    union { float f; unsigned u; } v; v.f = x;
    return (unsigned short)(v.u >> 16);
}
__device__ __forceinline__ float bf2f(unsigned short x) {
    union { unsigned u; float f; } v; v.u = ((unsigned)x) << 16;
    return v.f;
}

// ---------------------------------------------------------------------------
// K1: LayerNorm -> bf16 h. One wave per row (D=512), 4 rows/block.
// ---------------------------------------------------------------------------
__global__ __launch_bounds__(256) void k_ln(const float* __restrict__ inp,
                                            const float* __restrict__ nw,
                                            const float* __restrict__ nb,
                                            unsigned short* __restrict__ hbf) {
    int row  = blockIdx.x * 4 + (threadIdx.x >> 6);
    int lane = threadIdx.x & 63;
    const float4* p = (const float4*)(inp + (size_t)row * Dm);
    float4 v0 = p[lane];
    float4 v1 = p[lane + 64];
    float s = v0.x + v0.y + v0.z + v0.w + v1.x + v1.y + v1.z + v1.w;
    float q = v0.x * v0.x + v0.y * v0.y + v0.z * v0.z + v0.w * v0.w +
              v1.x * v1.x + v1.y * v1.y + v1.z * v1.z + v1.w * v1.w;
#pragma unroll
    for (int off = 32; off >= 1; off >>= 1) {
        s += __shfl_xor(s, off);
        q += __shfl_xor(q, off);
    }
    float mu = s * (1.f / Dm);
    float rs = rsqrtf(q * (1.f / Dm) - mu * mu + EPSf);
    int d0 = lane * 4, d1 = 256 + lane * 4;
    float4 w0 = *(const float4*)&nw[d0], w1 = *(const float4*)&nw[d1];
    float4 b0 = *(const float4*)&nb[d0], b1 = *(const float4*)&nb[d1];
    ushort4 o0, o1;
    o0.x = f2bf((v0.x - mu) * rs * w0.x + b0.x);
    o0.y = f2bf((v0.y - mu) * rs * w0.y + b0.y);
    o0.z = f2bf((v0.z - mu) * rs * w0.z + b0.z);
    o0.w = f2bf((v0.w - mu) * rs * w0.w + b0.w);
    o1.x = f2bf((v1.x - mu) * rs * w1.x + b1.x);
    o1.y = f2bf((v1.y - mu) * rs * w1.y + b1.y);
    o1.z = f2bf((v1.z - mu) * rs * w1.z + b1.z);
    o1.w = f2bf((v1.w - mu) * rs * w1.w + b1.w);
    *(ushort4*)&hbf[(size_t)row * Dm + d0] = o0;
    *(ushort4*)&hbf[(size_t)row * Dm + d1] = o1;
}

// ---------------------------------------------------------------------------
// K1b: merged fp32 -> bf16 cast of all four weight tensors. Quad-indexed.
// ---------------------------------------------------------------------------
__global__ __launch_bounds__(256) void k_castall(
    const float* __restrict__ Win,  unsigned short* __restrict__ wbi,
    const float* __restrict__ Wout, unsigned short* __restrict__ wbo,
    const float* __restrict__ xpf,  unsigned short* __restrict__ xpbf,
    const float* __restrict__ xpr,  unsigned short* __restrict__ xpbr) {
    size_t q = (size_t)blockIdx.x * 256 + threadIdx.x;  // quad index
    const float* src; unsigned short* dst; size_t off;
    if (q < 262144)      { src = Win;  dst = wbi;  off = q; }
    else if (q < 393216) { src = Wout; dst = wbo;  off = q - 262144; }
    else if (q < 409600) { src = xpf;  dst = xpbf; off = q - 393216; }
    else                 { src = xpr;  dst = xpbr; off = q - 409600; }
    float4 v = ((const float4*)src)[off];
    ushort4 o;
    o.x = f2bf(v.x); o.y = f2bf(v.y); o.z = f2bf(v.z); o.w = f2bf(v.w);
    ((ushort4*)dst)[off] = o;
}

// ---------------------------------------------------------------------------
// K2: in_proj bf16 MFMA GEMM.  xz[b][m][n] = sum_k W[m][k] * h[b*L+n][k]
// ---------------------------------------------------------------------------
__global__ __launch_bounds__(256) void k_mfma_inproj(
    const unsigned short* __restrict__ Wbf,  // (2048,512) bf16
    const unsigned short* __restrict__ hbf,  // (8192,512) bf16
    unsigned short* __restrict__ xz)         // (4,2048,2048) bf16
{
    const int b  = blockIdx.z;
    const int m0 = blockIdx.x * 128;
    const int n0 = blockIdx.y * 128;
    __shared__ __align__(16) unsigned short lA[128 * LDS_S];
    __shared__ __align__(16) unsigned short lB[128 * LDS_S];
    const int tid  = threadIdx.x;
    const int lane = tid & 63;
    const int w    = tid >> 6;
    const int wr   = w >> 1, wc = w & 1;

    f32x4 acc[4][4] = {};

    const unsigned short* hb = hbf + ((size_t)b * Lc + n0) * Dm;
    const unsigned short* Wb = Wbf + (size_t)m0 * Dm;

    for (int k0 = 0; k0 < Dm; k0 += 32) {
#pragma unroll
        for (int i = 0; i < 2; i++) {
            int c = tid + i * 256;            // 512 16B-chunks per tile
            int row = c >> 2, col = (c & 3) * 8;
            *(uint4*)&lA[row * LDS_S + col] = *(const uint4*)&Wb[(size_t)row * Dm + k0 + col];
            *(uint4*)&lB[row * LDS_S + col] = *(const uint4*)&hb[(size_t)row * Dm + k0 + col];
        }
        __syncthreads();
        bf16x8 aF[4], bF[4];
#pragma unroll
        for (int f = 0; f < 4; f++) {
            aF[f] = *(bf16x8*)&lA[(wr * 64 + f * 16 + (lane & 15)) * LDS_S + (lane >> 4) * 8];
            bF[f] = *(bf16x8*)&lB[(wc * 64 + f * 16 + (lane & 15)) * LDS_S + (lane >> 4) * 8];
        }
#pragma unroll
        for (int i = 0; i < 4; i++)
#pragma unroll
            for (int j = 0; j < 4; j++)
                acc[i][j] = __builtin_amdgcn_mfma_f32_16x16x32_bf16(aF[i], bF[j], acc[i][j], 0, 0, 0);
        __syncthreads();
    }
    unsigned short* Cb = xz + (size_t)b * 2048 * Lc;
#pragma unroll
    for (int i = 0; i < 4; i++) {
        int mbase = m0 + wr * 64 + i * 16 + (lane >> 4) * 4;
#pragma unroll
        for (int j = 0; j < 4; j++) {
            int nn = n0 + wc * 64 + j * 16 + (lane & 15);
#pragma unroll
            for (int r = 0; r < 4; r++)
                Cb[(size_t)(mbase + r) * Lc + nn] = f2bf(acc[i][j][r]);
        }
    }
}

// ---------------------------------------------------------------------------
// K3: tiled causal depthwise conv (K=4) + SiLU on bf16 xz.
// Emits xcT [b][L][e] bf16 via LDS transpose tile.
// ---------------------------------------------------------------------------
__global__ __launch_bounds__(256) void k_conv(const unsigned short* __restrict__ xz,
                                              const float* __restrict__ cw,
                                              const float* __restrict__ cb,
                                              unsigned short* __restrict__ xcT,
                                              int rev) {
    const int b  = blockIdx.z;
    const int e0 = blockIdx.y * 16;
    const int t0 = blockIdx.x * 64;
    const int tid = threadIdx.x;
    const int g = tid >> 4;
    const int n = tid & 15;
    const int e = e0 + g;
    const int j0 = t0 + n * 4;

    __shared__ unsigned short sY[64][20];   // stride 40 B: ushort4-aligned rows

    const unsigned short* x = xz + ((size_t)b * 2048 + e) * Lc;
    float w0 = cw[e * 4], w1 = cw[e * 4 + 1], w2 = cw[e * 4 + 2], w3 = cw[e * 4 + 3];
    float bias = cb[e];

    float v[8];  // xin[j0-4 .. j0+3] (xin = x or reversed x)
    if (!rev) {
        ushort4 cur = *(const ushort4*)&x[j0];
        v[4] = bf2f(cur.x); v[5] = bf2f(cur.y); v[6] = bf2f(cur.z); v[7] = bf2f(cur.w);
        if (j0 >= 4) {
            ushort4 prv = *(const ushort4*)&x[j0 - 4];
            v[0] = bf2f(prv.x); v[1] = bf2f(prv.y); v[2] = bf2f(prv.z); v[3] = bf2f(prv.w);
        } else { v[0] = v[1] = v[2] = v[3] = 0.f; }
    } else {
        ushort4 c4 = *(const ushort4*)&x[Lc - 4 - j0];
        v[4] = bf2f(c4.w); v[5] = bf2f(c4.z); v[6] = bf2f(c4.y); v[7] = bf2f(c4.x);
        if (j0 >= 4) {
            ushort4 p4 = *(const ushort4*)&x[Lc - j0];
            v[0] = bf2f(p4.w); v[1] = bf2f(p4.z); v[2] = bf2f(p4.y); v[3] = bf2f(p4.x);
        } else { v[0] = v[1] = v[2] = v[3] = 0.f; }
    }

#pragma unroll
    for (int jj = 0; jj < 4; jj++) {
        float a = bias + w0 * v[jj + 1] + w1 * v[jj + 2] + w2 * v[jj + 3] + w3 * v[jj + 4];
        sY[n * 4 + jj][g] = f2bf(siluf(a));
    }
    __syncthreads();

    int row = tid >> 2;
    int c4  = (tid & 3) * 4;
    ushort4 tv = *(ushort4*)&sY[row][c4];
    *(ushort4*)&xcT[((size_t)b * Lc + t0 + row) * Ei + e0 + c4] = tv;
}

// ---------------------------------------------------------------------------
// K4: x_proj bf16 MFMA GEMM: xdbl[b][m][n] = sum_e xpw[m][e] * xcT[b][n][e]
// Output bf16.
// ---------------------------------------------------------------------------
__global__ __launch_bounds__(256) void k_mfma_xdbl(
    const unsigned short* __restrict__ xpb,  // (64,1024) bf16
    const unsigned short* __restrict__ xcT,  // (4,2048,1024) bf16
    unsigned short* __restrict__ xdbl)       // (4,64,2048) bf16
{
    const int n0 = blockIdx.x * 128;
    const int b  = blockIdx.y;
    __shared__ __align__(16) unsigned short lA[64 * LDS_S];
    __shared__ __align__(16) unsigned short lB[128 * LDS_S];
    const int tid  = threadIdx.x;
    const int lane = tid & 63;
    const int w    = tid >> 6;

    f32x4 acc[4][2] = {};

    const unsigned short* yb = xcT + ((size_t)b * Lc + n0) * Ei;

    for (int k0 = 0; k0 < Ei; k0 += 32) {
        {
            int c = tid;
            int row = c >> 2, col = (c & 3) * 8;
            *(uint4*)&lA[row * LDS_S + col] = *(const uint4*)&xpb[(size_t)row * Ei + k0 + col];
        }
#pragma unroll
        for (int i = 0; i < 2; i++) {
            int c = tid + i * 256;
            int row = c >> 2, col = (c & 3) * 8;
            *(uint4*)&lB[row * LDS_S + col] = *(const uint4*)&yb[(size_t)row * Ei + k0 + col];
        }
        __syncthreads();
        bf16x8 aF[4], bF[2];
#pragma unroll
        for (int f = 0; f < 4; f++)
            aF[f] = *(bf16x8*)&lA[(f * 16 + (lane & 15)) * LDS_S + (lane >> 4) * 8];
#pragma unroll
        for (int f = 0; f < 2; f++)
            bF[f] = *(bf16x8*)&lB[(w * 32 + f * 16 + (lane & 15)) * LDS_S + (lane >> 4) * 8];
#pragma unroll
        for (int i = 0; i < 4; i++)
#pragma unroll
            for (int j = 0; j < 2; j++)
                acc[i][j] = __builtin_amdgcn_mfma_f32_16x16x32_bf16(aF[i], bF[j], acc[i][j], 0, 0, 0);
        __syncthreads();
    }
    unsigned short* xd = xdbl + (size_t)b * 64 * Lc;
#pragma unroll
    for (int i = 0; i < 4; i++) {
        int mbase = i * 16 + (lane >> 4) * 4;
#pragma unroll
        for (int j = 0; j < 2; j++) {
            int nn = n0 + w * 32 + j * 16 + (lane & 15);
#pragma unroll
            for (int r = 0; r < 4; r++)
                xd[(size_t)(mbase + r) * Lc + nn] = f2bf(acc[i][j][r]);
        }
    }
}

// ---------------------------------------------------------------------------
// K4b: dt = softplus(dtw @ dt_low + bias).  Output bf16 [b][t][e] via LDS
// transpose tile.  Block: 16 e x 64 t.
// ---------------------------------------------------------------------------
__global__ __launch_bounds__(256) void k_dt(
    const unsigned short* __restrict__ xdbl, // (4,64,2048) bf16; rows 0..31 dt_low
    const float* __restrict__ dtw,   // (1024,32)
    const float* __restrict__ dtb,   // (1024)
    unsigned short* __restrict__ dt16) // (4,2048,1024) bf16 [t][e]
{
    const int b  = blockIdx.z;
    const int e0 = blockIdx.y * 16;
    const int t0 = blockIdx.x * 64;
    const int tid = threadIdx.x;
    const int g = tid >> 4;          // local e
    const int n = tid & 15;          // t-quad selector
    const int e = e0 + g;

    __shared__ float sW[16][33];
    __shared__ float sDtl[32][68];
    __shared__ unsigned short sT[64][20];

    for (int i = tid; i < 512; i += 256)
        sW[i >> 5][i & 31] = dtw[(size_t)(e0 + (i >> 5)) * 32 + (i & 31)];

    const unsigned short* xdb = xdbl + (size_t)b * 64 * Lc;
#pragma unroll
    for (int f = 0; f < 2; f++) {
        int fi = tid * 2 + f;            // 512 quad slots (32 rows x 16 quads)
        int row = fi >> 4, c4 = (fi & 15) * 4;
        ushort4 q = *(const ushort4*)&xdb[(size_t)row * Lc + t0 + c4];
        *(float4*)&sDtl[row][c4] = make_float4(bf2f(q.x), bf2f(q.y), bf2f(q.z), bf2f(q.w));
    }
    __syncthreads();

    const float bias = dtb[e];
#pragma unroll
    for (int jj = 0; jj < 4; jj++) {
        int tt = n * 4 + jj;
        float a = bias;
#pragma unroll
        for (int r = 0; r < 32; r++) a += sDtl[r][tt] * sW[g][r];
        sT[tt][g] = f2bf(softplusf(a));
    }
    __syncthreads();

    int row = tid >> 2;
    int c4  = (tid & 3) * 4;
    ushort4 tv = *(ushort4*)&sT[row][c4];
    *(ushort4*)&dt16[((size_t)b * Lc + t0 + row) * Ei + e0 + c4] = tv;
}

// ---------------------------------------------------------------------------
// K5a: scan pass 1 — per-chunk affine transform (P = prod dA, S = local h).
// XCD-swizzled blockIdx; sDu precomputed at stage time.
// ---------------------------------------------------------------------------
__global__ __launch_bounds__(256) void k_scan_p1(
    const unsigned short* __restrict__ xcT,   // u bf16 [b][t][e]
    const unsigned short* __restrict__ xdbl,  // bf16 (4,64,2048)
    const unsigned short* __restrict__ dt16,  // bf16 [b][t][e]
    const float* __restrict__ Alog,
    float* __restrict__ Pbuf,          // [NCH][4][1024][16]
    float* __restrict__ Sbuf)
{
    const int nb  = NCH * 256;
    const int raw = blockIdx.x;
    const int bx  = (raw % NXCD) * (nb / NXCD) + raw / NXCD;   // XCD swizzle
    const int c  = bx >> 8;
    const int j  = bx & 255;
    const int b  = j >> 6;
    const int e0 = (j & 63) << 4;
    const int tid = threadIdx.x;
    const int g = tid >> 4;
    const int n = tid & 15;
    const int e = e0 + g;
    const int srow = tid >> 2;
    const int sc4  = (tid & 3) * 4;

    __shared__ float sDt[64][20];
    __shared__ float sDu[64][20];
    __shared__ float sB[16][68];

    const float A_n = -__expf(Alog[(size_t)e * Ns + n]);
    float h = 0.f, Pa = 1.f;

    const unsigned short* uT = xcT + (size_t)b * Lc * Ei;
    const unsigned short* dT = dt16 + (size_t)b * Lc * Ei;
    const unsigned short* xdb = xdbl + (size_t)b * 64 * Lc;

    const int tbeg = c * TCH;
    for (int t0 = tbeg; t0 < tbeg + TCH; t0 += 64) {
        ushort4 uu = *(const ushort4*)&uT[(size_t)(t0 + srow) * Ei + e0 + sc4];
        ushort4 dd = *(const ushort4*)&dT[(size_t)(t0 + srow) * Ei + e0 + sc4];
        float4 dtq = make_float4(bf2f(dd.x), bf2f(dd.y), bf2f(dd.z), bf2f(dd.w));
        *(float4*)&sDt[srow][sc4] = dtq;
        *(float4*)&sDu[srow][sc4] = make_float4(dtq.x * bf2f(uu.x), dtq.y * bf2f(uu.y),
                                                dtq.z * bf2f(uu.z), dtq.w * bf2f(uu.w));
        {   // B row stage: lane (g,n) reads row 32+g, cols t0+n*4 (coalesced)
            ushort4 bb = *(const ushort4*)&xdb[(size_t)(32 + g) * Lc + t0 + n * 4];
            *(float4*)&sB[g][n * 4] = make_float4(bf2f(bb.x), bf2f(bb.y), bf2f(bb.z), bf2f(bb.w));
        }
        __syncthreads();
#pragma unroll
        for (int tt = 0; tt < 64; tt++) {
            float dA = __expf(sDt[tt][g] * A_n);
            h  = fmaf(dA, h, sDu[tt][g] * sB[n][tt]);
            Pa *= dA;
        }
        __syncthreads();
    }
    size_t idx = ((size_t)(c * 4 + b) * 1024 + e) * 16 + n;
    Pbuf[idx] = Pa;
    Sbuf[idx] = h;
}

// ---------------------------------------------------------------------------
// K5c: scan pass 2 — all LDS planes bf16 (25.5 KB -> 6 blocks/CU; values are
// already bf16-rounded in memory so fp32 LDS bought no precision). sP stored
// bf16-truncated. XCD-swizzled; folded h_in composition.
// ---------------------------------------------------------------------------
__global__ __launch_bounds__(256, 6) void k_scan_p2(
    const unsigned short* __restrict__ xcT,   // u bf16 [b][t][e]
    const unsigned short* __restrict__ xdbl,  // bf16 (4,64,2048)
    const unsigned short* __restrict__ xz,    // bf16; z rows Ei..2Ei-1
    const unsigned short* __restrict__ dt16,  // bf16 [b][t][e]
    const float* __restrict__ Alog,
    const float* __restrict__ Dp,
    const float* __restrict__ Pbuf,    // [NCH][4][1024][16]
    const float* __restrict__ Sbuf,
    unsigned short* __restrict__ ybf,  // (4,2048,1024) bf16
    int rev)
{
    const int nb  = NCH * 256;
    const int raw = blockIdx.x;
    const int bx  = (raw % NXCD) * (nb / NXCD) + raw / NXCD;   // XCD swizzle
    const int c  = bx >> 8;
    const int j  = bx & 255;
    const int b  = j >> 6;
    const int e0 = (j & 63) << 4;
    const int tid = threadIdx.x;
    const int g = tid >> 4;
    const int n = tid & 15;
    const int e = e0 + g;
    const int srow = tid >> 2;
    const int sc4  = (tid & 3) * 4;

    __shared__ unsigned short sDt[64][20];
    __shared__ unsigned short sDu[64][20];
    __shared__ unsigned short sU[64][20];
    __shared__ unsigned short sB[16][68];
    __shared__ unsigned short sC[16][68];
    __shared__ unsigned short sP[16][17][20];
    __shared__ unsigned short sY[64][20];

    const float A_n = -__expf(Alog[(size_t)e * Ns + n]);
    const float Dv  = Dp[e];

    // folded mid kernel: compose h_in from chunks 0..c-1
    float h = 0.f;
    for (int cc = 0; cc < c; cc++) {
        size_t pidx = ((size_t)(cc * 4 + b) * 1024 + e) * 16 + n;
        h = Sbuf[pidx] + Pbuf[pidx] * h;
    }

    const unsigned short* uT = xcT + (size_t)b * Lc * Ei;
    const unsigned short* dT = dt16 + (size_t)b * Lc * Ei;
    const unsigned short* zp = xz + ((size_t)b * 2048 + Ei + e) * Lc;
    const unsigned short* xdb = xdbl + (size_t)b * 64 * Lc;

    const int tbeg = c * TCH;
    for (int t0 = tbeg; t0 < tbeg + TCH; t0 += 64) {
        ushort4 uu = *(const ushort4*)&uT[(size_t)(t0 + srow) * Ei + e0 + sc4];
        ushort4 dd = *(const ushort4*)&dT[(size_t)(t0 + srow) * Ei + e0 + sc4];
        *(ushort4*)&sU[srow][sc4]  = uu;
        *(ushort4*)&sDt[srow][sc4] = dd;
        ushort4 du;
        du.x = f2bf(bf2f(dd.x) * bf2f(uu.x));
        du.y = f2bf(bf2f(dd.y) * bf2f(uu.y));
        du.z = f2bf(bf2f(dd.z) * bf2f(uu.z));
        du.w = f2bf(bf2f(dd.w) * bf2f(uu.w));
        *(ushort4*)&sDu[srow][sc4] = du;
        {
            ushort4 bb  = *(const ushort4*)&xdb[(size_t)(32 + g) * Lc + t0 + n * 4];
            ushort4 cc4 = *(const ushort4*)&xdb[(size_t)(48 + g) * Lc + t0 + n * 4];
            *(ushort4*)&sB[g][n * 4] = bb;
            *(ushort4*)&sC[g][n * 4] = cc4;
        }
        __syncthreads();

#pragma unroll
        for (int s = 0; s < 4; s++) {
#pragma unroll
            for (int t2 = 0; t2 < 16; t2++) {
                int tt = s * 16 + t2;
                float dA = __expf(bf2f(sDt[tt][g]) * A_n);
                h = fmaf(dA, h, bf2f(sDu[tt][g]) * bf2f(sB[n][tt]));
                sP[g][t2][n] = f2bf_trunc(h * bf2f(sC[n][tt]));
            }
            // same-wave transposed reduce: lane (g,n) sums states for tt=s*16+n
            ushort4 q0 = *(ushort4*)&sP[g][n][0];
            ushort4 q1 = *(ushort4*)&sP[g][n][4];
            ushort4 q2 = *(ushort4*)&sP[g][n][8];
            ushort4 q3 = *(ushort4*)&sP[g][n][12];
            float acc = ((bf2f(q0.x) + bf2f(q0.y)) + (bf2f(q0.z) + bf2f(q0.w))) +
                        ((bf2f(q1.x) + bf2f(q1.y)) + (bf2f(q1.z) + bf2f(q1.w))) +
                        ((bf2f(q2.x) + bf2f(q2.y)) + (bf2f(q2.z) + bf2f(q2.w))) +
                        ((bf2f(q3.x) + bf2f(q3.y)) + (bf2f(q3.z) + bf2f(q3.w)));
            int tt = s * 16 + n;
            int t  = t0 + tt;
            int gi = rev ? (Lc - 1 - t) : t;
            float val = (acc + Dv * bf2f(sU[tt][g])) * siluf(bf2f(zp[gi]));
            sY[rev ? (63 - tt) : tt][g] = f2bf(val);
        }
        __syncthreads();

        // coalesced tile write
        {
            int trow = rev ? (Lc - 64 - t0 + srow) : (t0 + srow);
            size_t gidx = ((size_t)b * Lc + trow) * Ei + e0 + sc4;
            ushort4 tv = *(ushort4*)&sY[srow][sc4];
            if (rev) {
                ushort4 ov = *(ushort4*)&ybf[gidx];
                tv.x = f2bf(bf2f(tv.x) + bf2f(ov.x));
                tv.y = f2bf(bf2f(tv.y) + bf2f(ov.y));
                tv.z = f2bf(bf2f(tv.z) + bf2f(ov.z));
                tv.w = f2bf(bf2f(tv.w) + bf2f(ov.w));
            }
            *(ushort4*)&ybf[gidx] = tv;
        }
        __syncthreads();
    }
}

// ---------------------------------------------------------------------------
// K6: out_proj bf16 MFMA GEMM. out[b][n][m] = sum_e Wout[m][e]*ybf[b][n][e]
// ---------------------------------------------------------------------------
__global__ __launch_bounds__(256) void k_mfma_outproj(
    const unsigned short* __restrict__ Wbf,  // (512,1024) bf16
    const unsigned short* __restrict__ ybf,  // (4,2048,1024) bf16
    float* __restrict__ out)                 // (4,2048,512)
{
    const int b  = blockIdx.z;
    const int m0 = blockIdx.x * 64;
    const int n0 = blockIdx.y * 128;
    __shared__ __align__(16) unsigned short lA[64 * LDS_S];
    __shared__ __align__(16) unsigned short lB[128 * LDS_S];
    const int tid  = threadIdx.x;
    const int lane = tid & 63;
    const int w    = tid >> 6;
    const int wr   = w >> 1, wc = w & 1;

    f32x4 acc[2][4] = {};

    const unsigned short* yb = ybf + ((size_t)b * Lc + n0) * Ei;
    const unsigned short* Wb = Wbf + (size_t)m0 * Ei;

    for (int k0 = 0; k0 < Ei; k0 += 32) {
        {
            int c = tid;
            int row = c >> 2, col = (c & 3) * 8;
            *(uint4*)&lA[row * LDS_S + col] = *(const uint4*)&Wb[(size_t)row * Ei + k0 + col];
        }
#pragma unroll
        for (int i = 0; i < 2; i++) {
            int c = tid + i * 256;
            int row = c >> 2, col = (c & 3) * 8;
            *(uint4*)&lB[row * LDS_S + col] = *(const uint4*)&yb[(size_t)row * Ei + k0 + col];
        }
        __syncthreads();
        bf16x8 aF[2], bF[4];
#pragma unroll
        for (int f = 0; f < 2; f++)
            aF[f] = *(bf16x8*)&lA[(wr * 32 + f * 16 + (lane & 15)) * LDS_S + (lane >> 4) * 8];
#pragma unroll
        for (int f = 0; f < 4; f++)
            bF[f] = *(bf16x8*)&lB[(wc * 64 + f * 16 + (lane & 15)) * LDS_S + (lane >> 4) * 8];
#pragma unroll
        for (int i = 0; i < 2; i++)
#pragma unroll
            for (int j = 0; j < 4; j++)
                acc[i][j] = __builtin_amdgcn_mfma_f32_16x16x32_bf16(aF[i], bF[j], acc[i][j], 0, 0, 0);
        __syncthreads();
    }
    float* ob = out + (size_t)b * Lc * Dm;
#pragma unroll
    for (int i = 0; i < 2; i++) {
        int mm = m0 + wr * 32 + i * 16 + (lane >> 4) * 4;
#pragma unroll
        for (int j = 0; j < 4; j++) {
            int nn = n0 + wc * 64 + j * 16 + (lane & 15);
            *(f32x4*)&ob[(size_t)nn * Dm + mm] = acc[i][j];
        }
    }
}

// ---------------------------------------------------------------------------
// K7: fused residual add + RMSNorm (in place on d_out).
// ---------------------------------------------------------------------------
__global__ __launch_bounds__(256) void k_rms(float* __restrict__ out,
                                             const float* __restrict__ resid,
                                             const float* __restrict__ w) {
    int row  = blockIdx.x * 4 + (threadIdx.x >> 6);
    int lane = threadIdx.x & 63;
    float4* po = (float4*)(out + (size_t)row * Dm);
    const float4* pr = (const float4*)(resid + (size_t)row * Dm);
    const float4* pw = (const float4*)w;
    float4 a0 = po[lane], a1 = po[lane + 64];
    float4 r0 = pr[lane], r1 = pr[lane + 64];
    a0.x += r0.x; a0.y += r0.y; a0.z += r0.z; a0.w += r0.w;
    a1.x += r1.x; a1.y += r1.y; a1.z += r1.z; a1.w += r1.w;
    float q = a0.x * a0.x + a0.y * a0.y + a0.z * a0.z + a0.w * a0.w +
              a1.x * a1.x + a1.y * a1.y + a1.z * a1.z + a1.w * a1.w;
#pragma unroll
    for (int off = 32; off >= 1; off >>= 1) q += __shfl_xor(q, off);
    float scale = rsqrtf(q * (1.f / Dm) + EPSf);
    float4 w0 = pw[lane], w1 = pw[lane + 64];
    a0.x *= scale * w0.x; a0.y *= scale * w0.y; a0.z *= scale * w0.z; a0.w *= scale * w0.w;
    a1.x *= scale * w1.x; a1.y *= scale * w1.y; a1.z *= scale * w1.z; a1.w *= scale * w1.w;
    po[lane] = a0;
    po[lane + 64] = a1;
}

// ---------------------------------------------------------------------------
extern "C" void kernel_launch(void* const* d_in, const int* in_sizes, int n_in,
                              void* d_out, int out_size, void* d_ws, size_t ws_size,
                              hipStream_t stream) {
    const float* inp   = (const float*)d_in[0];
    const float* nw    = (const float*)d_in[1];
    const float* nbv   = (const float*)d_in[2];
    const float* Win   = (const float*)d_in[3];
    const float* cwf   = (const float*)d_in[4];
    const float* cbf   = (const float*)d_in[5];
    const float* xpwf  = (const float*)d_in[6];
    const float* dtwf  = (const float*)d_in[7];
    const float* dtbf  = (const float*)d_in[8];
    const float* Alogf = (const float*)d_in[9];
    const float* Df    = (const float*)d_in[10];
    const float* cwr   = (const float*)d_in[11];
    const float* cbr   = (const float*)d_in[12];
    const float* xpwr  = (const float*)d_in[13];
    const float* dtwr  = (const float*)d_in[14];
    const float* dtbr  = (const float*)d_in[15];
    const float* Alogr = (const float*)d_in[16];
    const float* Dr    = (const float*)d_in[17];
    const float* Wout  = (const float*)d_in[18];
    const float* nfw   = (const float*)d_in[19];
    float* outp = (float*)d_out;

    // workspace layout (ushort units)
    unsigned short* xz   = (unsigned short*)d_ws;            // 16,777,216
    unsigned short* xdbl = xz + (size_t)16777216;            //    524,288
    unsigned short* xcT  = xdbl + (size_t)524288;            //  8,388,608
    unsigned short* ybf  = xcT + (size_t)8388608;            //  8,388,608
    unsigned short* hbf  = ybf + (size_t)8388608;            //  4,194,304
    unsigned short* wbi  = hbf + (size_t)4194304;            //  1,048,576
    unsigned short* wbo  = wbi + (size_t)1048576;            //    524,288
    unsigned short* dt16 = wbo + (size_t)524288;             //  8,388,608
    unsigned short* xpbf = dt16 + (size_t)8388608;           //     65,536
    unsigned short* xpbr = xpbf + (size_t)65536;             //     65,536

    // P/S scratch lives in d_out (4.19M floats; overwritten by out_proj).
    float* Pb = outp;
    float* Sb = outp + 1048576;

    k_ln<<<2048, 256, 0, stream>>>(inp, nw, nbv, hbf);
    k_castall<<<1664, 256, 0, stream>>>(Win, wbi, Wout, wbo, xpwf, xpbf, xpwr, xpbr);
    k_mfma_inproj<<<dim3(16, 16, 4), 256, 0, stream>>>(wbi, hbf, xz);

    // forward branch
    k_conv<<<dim3(32, 64, 4), 256, 0, stream>>>(xz, cwf, cbf, xcT, 0);
    k_mfma_xdbl<<<dim3(16, 4), 256, 0, stream>>>(xpbf, xcT, xdbl);
    k_dt<<<dim3(32, 64, 4), 256, 0, stream>>>(xdbl, dtwf, dtbf, dt16);
    k_scan_p1<<<NCH * 256, 256, 0, stream>>>(xcT, xdbl, dt16, Alogf, Pb, Sb);
    k_scan_p2<<<NCH * 256, 256, 0, stream>>>(xcT, xdbl, xz, dt16, Alogf, Df, Pb, Sb, ybf, 0);

    // reverse branch (index-reversed, accumulates into ybf)
    k_conv<<<dim3(32, 64, 4), 256, 0, stream>>>(xz, cwr, cbr, xcT, 1);
    k_mfma_xdbl<<<dim3(16, 4), 256, 0, stream>>>(xpbr, xcT, xdbl);
    k_dt<<<dim3(32, 64, 4), 256, 0, stream>>>(xdbl, dtwr, dtbr, dt16);
    k_scan_p1<<<NCH * 256, 256, 0, stream>>>(xcT, xdbl, dt16, Alogr, Pb, Sb);
    k_scan_p2<<<NCH * 256, 256, 0, stream>>>(xcT, xdbl, xz, dt16, Alogr, Dr, Pb, Sb, ybf, 1);

    k_mfma_outproj<<<dim3(8, 16, 4), 256, 0, stream>>>(wbo, ybf, outp);
    k_rms<<<2048, 256, 0, stream>>>(outp, inp, nfw);
}